// Round 9
// baseline (461.101 us; speedup 1.0000x reference)
//
#include <hip/hip_runtime.h>
#include <hip/hip_bf16.h>

// MambaSplit: B=4,C=128,H=W=64, D=64, DI=128, N=16, R=4, K=4, L=4096, E=2*B=8
// Round-21: round-8 structure (439us best: a2tab + LDS-staged dts4/B/C scan)
// + weight tables pre-converted to f32 (kprep: xpwF/opwF/ipwF); k5 and k7b
// drop their sW/sWo LDS staging and read weights directly from global with
// wave-uniform broadcast float4 loads (tables are L1-resident). k5 LDS
// 53->34KB (3->4 blocks/CU), k7b 60->27KB (2->5 blocks/CU). k6 untouched.

__device__ __forceinline__ float LD(const void* p, size_t i, bool isb) {
  if (isb) {
    unsigned short u = ((const unsigned short*)p)[i];
    return __uint_as_float(((unsigned)u) << 16);
  }
  return ((const float*)p)[i];
}
__device__ __forceinline__ unsigned short f2bf(float f) {
  unsigned u = __float_as_uint(f);
  u = (u + 0x7FFFu + ((u >> 16) & 1u)) >> 16;
  return (unsigned short)u;
}
__device__ __forceinline__ float silu_(float x) { return x / (1.f + __expf(-x)); }
__device__ __forceinline__ float softplus_(float x) {
  return x > 20.f ? x : __logf(1.f + __expf(x));
}
#define EXP2R(x) __builtin_amdgcn_exp2f(x)

// ---------------- detector: bf16 vs f32 input encoding ----------------
__global__ void kdet(const void* x, int* flag) {
  if (threadIdx.x == 0 && blockIdx.x == 0) {
    const unsigned short* xs = (const unsigned short*)x;
    int bad = 0;
    for (int i = 0; i < 64; ++i) {
      int e = (xs[2 * i] >> 7) & 0xFF;
      if (e > 150 || e < 100) bad++;
    }
    *flag = (bad >= 16) ? 0 : 1;
  }
}

// ---------------- KP: a2 table + f32 weight tables ----------------
__global__ __launch_bounds__(256) void kprep(
    const void* alog, const void* xpw, const void* opw, const void* ipw,
    const int* __restrict__ flag,
    float* __restrict__ a2tab, float* __restrict__ xpwF,
    float* __restrict__ opwF, float* __restrict__ ipwF)
{
  bool isb = (*flag != 0);
  int i = blockIdx.x * 256 + threadIdx.x;
  if (i < 8192)  a2tab[i] = -__expf(LD(alog, i, isb)) * 1.44269504f;
  if (i < 18432) xpwF[i] = LD(xpw, i, isb);   // (K,36,128)
  if (i < 8192)  opwF[i] = LD(opw, i, isb);   // (64,128)
  if (i < 16384) ipwF[i] = LD(ipw, i, isb);   // (256,64)
}

// ---------------- K0: dwconv(x) -> T1 (E,L,64) + LN -> T2 ----------------
__global__ __launch_bounds__(256) void k0_conv_ln(
    const void* x, const void* dww, const void* dwb, const void* lg, const void* lb,
    const int* __restrict__ flag,
    float* __restrict__ T1, float* __restrict__ T2)
{
  bool isb = (*flag != 0);
  int e = blockIdx.x >> 6, h = blockIdx.x & 63;
  int b = e & 3, br = e >> 2;
  int t = threadIdx.x;
  __shared__ float sIn[3][64][67];  // [row][d][1+w], w-halo zeroed
  for (int idx = t; idx < 3 * 64; idx += 256) {
    int r = idx >> 6, d = idx & 63;
    sIn[r][d][0] = 0.f; sIn[r][d][65] = 0.f;
  }
  for (int idx = t; idx < 3 * 64 * 64; idx += 256) {
    int r = idx >> 12, rem = idx & 4095, d = rem >> 6, w = rem & 63;
    int hh = h + r - 1;
    float v = 0.f;
    if (hh >= 0 && hh < 64) v = LD(x, ((size_t)(b * 128 + br * 64 + d) * 64 + hh) * 64 + w, isb);
    sIn[r][d][1 + w] = v;
  }
  __syncthreads();
  int w = t >> 2, g = t & 3;
  float vals[16]; float psum = 0.f, psq = 0.f;
#pragma unroll
  for (int j = 0; j < 16; ++j) {
    int d = g * 16 + j, c = br * 64 + d;
    float s = LD(dwb, c, isb);
#pragma unroll
    for (int kh = 0; kh < 3; ++kh)
#pragma unroll
      for (int kw = 0; kw < 3; ++kw)
        s += LD(dww, c * 9 + kh * 3 + kw, isb) * sIn[kh][d][w + kw];
    vals[j] = s; psum += s; psq += s * s;
  }
  size_t base = ((size_t)e * 4096 + h * 64) * 64 + (size_t)t * 16;
#pragma unroll
  for (int j4 = 0; j4 < 4; ++j4) {
    float4 o; o.x = vals[j4*4]; o.y = vals[j4*4+1]; o.z = vals[j4*4+2]; o.w = vals[j4*4+3];
    *(float4*)(T1 + base + j4 * 4) = o;
  }
  __shared__ float sS[64][4], sQ[64][4];
  sS[w][g] = psum; sQ[w][g] = psq;
  __syncthreads();
  float m = (sS[w][0] + sS[w][1] + sS[w][2] + sS[w][3]) * (1.f / 64.f);
  float q = (sQ[w][0] + sQ[w][1] + sQ[w][2] + sQ[w][3]) * (1.f / 64.f);
  float rs = rsqrtf(q - m * m + 1e-5f);
#pragma unroll
  for (int j4 = 0; j4 < 4; ++j4) {
    float tmp[4];
#pragma unroll
    for (int jj = 0; jj < 4; ++jj) {
      int j = j4 * 4 + jj; int d = g * 16 + j;
      tmp[jj] = (vals[j] - m) * rs * LD(lg, d, isb) + LD(lb, d, isb);
    }
    float4 o; o.x = tmp[0]; o.y = tmp[1]; o.z = tmp[2]; o.w = tmp[3];
    *(float4*)(T2 + base + j4 * 4) = o;
  }
}

// ---------------- K2: in_proj GEMM  T2(32768,64) @ W^T(64,256) -> T3 / T4 ----------------
__global__ __launch_bounds__(256) void k2_inproj(
    const float* __restrict__ T2, const float* __restrict__ ipwF,
    float* __restrict__ T3, float* __restrict__ T4)
{
  int mt = blockIdx.x, ct = blockIdx.y;
  int t = threadIdx.x;
  __shared__ float sA[64][68];  // [d][l]
  __shared__ float sB[64][68];  // [d][c]
  int row0 = mt * 64;
  for (int q = t; q < 1024; q += 256) {
    int l = q >> 4, d4 = (q & 15) * 4;
    float4 v = *(const float4*)(T2 + (size_t)(row0 + l) * 64 + d4);
    sA[d4][l] = v.x; sA[d4+1][l] = v.y; sA[d4+2][l] = v.z; sA[d4+3][l] = v.w;
  }
  for (int q = t; q < 1024; q += 256) {
    int cl = q >> 4, d4 = (q & 15) * 4;
    float4 v = *(const float4*)(ipwF + (size_t)(ct * 64 + cl) * 64 + d4);
    sB[d4][cl] = v.x; sB[d4+1][cl] = v.y; sB[d4+2][cl] = v.z; sB[d4+3][cl] = v.w;
  }
  __syncthreads();
  int ty = t >> 4, tx = t & 15;
  float acc[4][4];
#pragma unroll
  for (int i = 0; i < 4; ++i)
#pragma unroll
    for (int j = 0; j < 4; ++j) acc[i][j] = 0.f;
  for (int kk = 0; kk < 64; ++kk) {
    float4 a = *(const float4*)&sA[kk][ty * 4];
    float4 bq = *(const float4*)&sB[kk][tx * 4];
    float aa[4] = {a.x, a.y, a.z, a.w}, bb[4] = {bq.x, bq.y, bq.z, bq.w};
#pragma unroll
    for (int i = 0; i < 4; ++i)
#pragma unroll
      for (int j = 0; j < 4; ++j) acc[i][j] += aa[i] * bb[j];
  }
  int c0 = ct * 64 + tx * 4;
#pragma unroll
  for (int i = 0; i < 4; ++i) {
    size_t row = (size_t)row0 + ty * 4 + i;
    float4 o;
    if (c0 < 128) {
      o.x = acc[i][0]; o.y = acc[i][1]; o.z = acc[i][2]; o.w = acc[i][3];
      *(float4*)(T3 + row * 128 + c0) = o;
    } else {
      o.x = silu_(acc[i][0]); o.y = silu_(acc[i][1]); o.z = silu_(acc[i][2]); o.w = silu_(acc[i][3]);
      *(float4*)(T4 + row * 128 + (c0 - 128)) = o;
    }
  }
}

// ---------------- K3: depthwise conv 3x3 + SiLU -> U0, and Ysum = sumDs*u ----------------
__global__ __launch_bounds__(256) void k3_conv2(
    const float* __restrict__ T3, const void* cw, const void* cb, const void* Ds,
    const int* __restrict__ flag,
    float* __restrict__ U0, float* __restrict__ Ysum)
{
  bool isb = (*flag != 0);
  int e = blockIdx.x >> 6, h = blockIdx.x & 63, dc = blockIdx.y;
  int t = threadIdx.x;
  __shared__ float sI[3][66][65];  // [row][1+w][d]
  for (int idx = t; idx < 3 * 2 * 64; idx += 256) {
    int r = idx / 128, rem = idx % 128, side = rem >> 6, d = rem & 63;
    sI[r][side * 65][d] = 0.f;
  }
  for (int idx = t; idx < 3 * 64 * 64; idx += 256) {
    int r = idx >> 12, rem = idx & 4095, w = rem >> 6, d = rem & 63;
    int hh = h + r - 1;
    float v = 0.f;
    if (hh >= 0 && hh < 64) v = T3[((size_t)e * 4096 + hh * 64 + w) * 128 + dc * 64 + d];
    sI[r][1 + w][d] = v;
  }
  __syncthreads();
  int d = t & 63, wq = t >> 6;
  int c2 = dc * 64 + d;
  float wt[9];
#pragma unroll
  for (int m = 0; m < 9; ++m) wt[m] = LD(cw, c2 * 9 + m, isb);
  float bias = LD(cb, c2, isb);
  float sd = LD(Ds, c2, isb) + LD(Ds, 128 + c2, isb) + LD(Ds, 256 + c2, isb) + LD(Ds, 384 + c2, isb);
  size_t eb = (size_t)e * 4096;
#pragma unroll
  for (int i = 0; i < 16; ++i) {
    int w = wq * 16 + i;
    float s = bias;
#pragma unroll
    for (int kh = 0; kh < 3; ++kh)
#pragma unroll
      for (int kw = 0; kw < 3; ++kw)
        s += wt[kh * 3 + kw] * sI[kh][w + kw][d];
    s = silu_(s);
    U0[(eb + h * 64 + w) * 128 + c2] = s;
    Ysum[(eb + h * 64 + w) * 128 + c2] = sd * s;
  }
}

// ---------------- K5: x_dbl einsum; weights direct from xpwF (wave-uniform bcast) ----------------
__global__ __launch_bounds__(256) void k5_xdbl(
    const float* __restrict__ U0,
    const float* __restrict__ xpwF,
    float* __restrict__ dts4, float* __restrict__ Bb2, float* __restrict__ Cb2)
{
  int lt = blockIdx.x;   // 64 tiles of 64 along L
  int ek = blockIdx.y;   // e*4+k
  int e = ek >> 2, k = ek & 3;
  int ls0 = lt * 64;
  int t = threadIdx.x;
  __shared__ float sU[64][132];   // [l][d]  (33.8KB only -> 4 blocks/CU)
  const bool rev = (k >= 2);
  const int trq = (k & 1);
  for (int idx = t; idx < 2048; idx += 256) {
    int l = idx >> 5, d4 = (idx & 31) * 4;
    int p = rev ? (4095 - ls0 - l) : (ls0 + l);
    int row = trq ? (((p & 63) << 6) | (p >> 6)) : p;
    float4 v = *(const float4*)(U0 + ((size_t)e * 4096 + row) * 128 + d4);
    *(float4*)&sU[l][d4] = v;
  }
  __syncthreads();
  int l = t & 63, cg = t >> 6;
  const float4* wbase = (const float4*)(xpwF + (size_t)k * 36 * 128);
  float acc[9];
#pragma unroll
  for (int j = 0; j < 9; ++j) acc[j] = 0.f;
  for (int dd = 0; dd < 32; ++dd) {
    float4 u4 = *(const float4*)&sU[l][dd * 4];
    float ua[4] = {u4.x, u4.y, u4.z, u4.w};
#pragma unroll
    for (int j = 0; j < 9; ++j) {
      float4 w4 = wbase[(cg * 9 + j) * 32 + dd];   // whole-wave broadcast, L1-resident
      acc[j] += ua[0] * w4.x + ua[1] * w4.y + ua[2] * w4.z + ua[3] * w4.w;
    }
  }
  size_t row = (size_t)ek * 4096 + ls0 + l;
  if (cg == 0) {
    float4 o; o.x = acc[0]; o.y = acc[1]; o.z = acc[2]; o.w = acc[3];
    *(float4*)(dts4 + row * 4) = o;
#pragma unroll
    for (int j = 4; j < 9; ++j) Bb2[row * 16 + (j - 4)] = acc[j];
  } else {
#pragma unroll
    for (int j = 0; j < 9; ++j) {
      int c = cg * 9 + j;
      if (c < 20) Bb2[row * 16 + (c - 4)] = acc[j];
      else Cb2[row * 16 + (c - 20)] = acc[j];
    }
  }
}

// ---------------- K6a: chunk-local scan, LDS-staged dts4/B -> Hsh + Sdl ----------------
template<int NSTEPS>
__global__ __launch_bounds__(128) void k6a_chunk(
    const float* __restrict__ U0,
    const float* __restrict__ dts4, const float* __restrict__ Bb2,
    const float* __restrict__ a2tab, const void* dtw, const void* dtb,
    const int* __restrict__ flag,
    float* __restrict__ Hsh, float* __restrict__ Sdl)
{
  bool isb = (*flag != 0);
  int chunk = blockIdx.x, ek = blockIdx.y;
  int e = ek >> 2, k = ek & 3;
  int d = threadIdx.x;
  int ls0 = chunk * NSTEPS;
  __shared__ float4 sDt[NSTEPS];        // 512B
  __shared__ float4 sB[NSTEPS * 4];     // 2KB
  {
    const float4* srcd = (const float4*)(dts4 + ((size_t)ek * 4096 + ls0) * 4);
    const float4* srcb = (const float4*)(Bb2 + ((size_t)ek * 4096 + ls0) * 16);
    if (d < NSTEPS) sDt[d] = srcd[d];
    sB[d] = srcb[d];
  }
  float a2[16];
  {
    const float4* ap = (const float4*)(a2tab + ((size_t)k * 128 + d) * 16);
#pragma unroll
    for (int n4 = 0; n4 < 4; ++n4) {
      float4 v = ap[n4];
      a2[n4*4+0] = v.x; a2[n4*4+1] = v.y; a2[n4*4+2] = v.z; a2[n4*4+3] = v.w;
    }
  }
  float w0 = LD(dtw, ((size_t)k * 128 + d) * 4 + 0, isb);
  float w1 = LD(dtw, ((size_t)k * 128 + d) * 4 + 1, isb);
  float w2 = LD(dtw, ((size_t)k * 128 + d) * 4 + 2, isb);
  float w3 = LD(dtw, ((size_t)k * 128 + d) * 4 + 3, isb);
  float bd = LD(dtb, k * 128 + d, isb);
  float h[16];
#pragma unroll
  for (int n = 0; n < 16; ++n) h[n] = 0.f;
  float sdelta = 0.f;
  const bool rv = (k >= 2);
  const int tq = (k & 1);
  const float* ubase = U0 + (size_t)e * 4096 * 128 + d;
  __syncthreads();
#pragma unroll 2
  for (int s = 0; s < NSTEPS; ++s) {
    float4 s4 = sDt[s];
    float xv = bd + w0 * s4.x + w1 * s4.y + w2 * s4.z + w3 * s4.w;
    float dlt = softplus_(xv);
    int p = ls0 + s;
    int r0 = rv ? (4095 - p) : p;
    int row = tq ? (((r0 & 63) << 6) | (r0 >> 6)) : r0;
    float uu = ubase[(size_t)row * 128];
    float du = dlt * uu;
    sdelta += dlt;
#pragma unroll
    for (int n4 = 0; n4 < 4; ++n4) {
      float4 b4 = sB[s * 4 + n4];
      h[n4*4+0] = fmaf(EXP2R(dlt * a2[n4*4+0]), h[n4*4+0], du * b4.x);
      h[n4*4+1] = fmaf(EXP2R(dlt * a2[n4*4+1]), h[n4*4+1], du * b4.y);
      h[n4*4+2] = fmaf(EXP2R(dlt * a2[n4*4+2]), h[n4*4+2], du * b4.z);
      h[n4*4+3] = fmaf(EXP2R(dlt * a2[n4*4+3]), h[n4*4+3], du * b4.w);
    }
  }
  float* hp = Hsh + (size_t)chunk * 65536 + (size_t)ek * 2048 + (size_t)d * 16;
#pragma unroll
  for (int n4 = 0; n4 < 4; ++n4) {
    float4 o; o.x = h[n4*4]; o.y = h[n4*4+1]; o.z = h[n4*4+2]; o.w = h[n4*4+3];
    *(float4*)(hp + n4 * 4) = o;
  }
  Sdl[(size_t)chunk * 4096 + ek * 128 + d] = sdelta;
}

// ---------------- K6b: carry scan; prodA recomputed from sdelta; exclusive Carry out ----------------
__global__ __launch_bounds__(256) void k6b_carry(
    const float* __restrict__ Hsh, const float* __restrict__ Sdl,
    const float* __restrict__ a2tab,
    float* __restrict__ Carry)
{
  int idx = blockIdx.x * 256 + threadIdx.x;   // 65536 = ek*2048 + d*16 + n
  int ek = idx >> 11;
  int k = ek & 3;
  float a2 = a2tab[(size_t)k * 2048 + (idx & 2047)];
  int sidx = ek * 128 + ((idx & 2047) >> 4);
  float carry = 0.f;
  for (int c0 = 0; c0 < 128; c0 += 8) {
    float hv[8], pA[8];
#pragma unroll
    for (int j = 0; j < 8; ++j) {
      hv[j] = Hsh[(size_t)(c0 + j) * 65536 + idx];
      pA[j] = Sdl[(size_t)(c0 + j) * 4096 + sidx];
    }
#pragma unroll
    for (int j = 0; j < 8; ++j) pA[j] = EXP2R(a2 * pA[j]);
#pragma unroll
    for (int j = 0; j < 8; ++j) {
      Carry[(size_t)(c0 + j) * 65536 + idx] = carry;   // exclusive prefix
      carry = fmaf(pA[j], carry, hv[j]);
    }
  }
}

// ---------------- K6c: seeded chunk scan, LDS-staged dts4/B/C; atomic y-merge ----------------
// u-read row == output row for every direction k (reversal+transpose fold).
template<int NSTEPS>
__global__ __launch_bounds__(128) void k6c_apply(
    const float* __restrict__ U0,
    float* __restrict__ Ysum, const float* __restrict__ dts4,
    const float* __restrict__ Bb2, const float* __restrict__ Cb2,
    const float* __restrict__ a2tab, const void* dtw, const void* dtb,
    const float* __restrict__ Carry, const int* __restrict__ flag)
{
  bool isb = (*flag != 0);
  int chunk = blockIdx.x, ek = blockIdx.y;
  int e = ek >> 2, k = ek & 3;
  int d = threadIdx.x;
  int ls0 = chunk * NSTEPS;
  __shared__ float4 sDt[NSTEPS];        // 512B
  __shared__ float4 sB[NSTEPS * 4];     // 2KB
  __shared__ float4 sC[NSTEPS * 4];     // 2KB
  {
    const float4* srcd = (const float4*)(dts4 + ((size_t)ek * 4096 + ls0) * 4);
    const float4* srcb = (const float4*)(Bb2 + ((size_t)ek * 4096 + ls0) * 16);
    const float4* srcc = (const float4*)(Cb2 + ((size_t)ek * 4096 + ls0) * 16);
    if (d < NSTEPS) sDt[d] = srcd[d];
    sB[d] = srcb[d];
    sC[d] = srcc[d];
  }
  float a2[16];
  {
    const float4* ap = (const float4*)(a2tab + ((size_t)k * 128 + d) * 16);
#pragma unroll
    for (int n4 = 0; n4 < 4; ++n4) {
      float4 v = ap[n4];
      a2[n4*4+0] = v.x; a2[n4*4+1] = v.y; a2[n4*4+2] = v.z; a2[n4*4+3] = v.w;
    }
  }
  float w0 = LD(dtw, ((size_t)k * 128 + d) * 4 + 0, isb);
  float w1 = LD(dtw, ((size_t)k * 128 + d) * 4 + 1, isb);
  float w2 = LD(dtw, ((size_t)k * 128 + d) * 4 + 2, isb);
  float w3 = LD(dtw, ((size_t)k * 128 + d) * 4 + 3, isb);
  float bd = LD(dtb, k * 128 + d, isb);
  float h[16];
  {
    const float* cp = Carry + (size_t)chunk * 65536 + (size_t)ek * 2048 + (size_t)d * 16;
#pragma unroll
    for (int n = 0; n < 16; ++n) h[n] = cp[n];
  }
  const bool rv = (k >= 2);
  const int tq = (k & 1);
  const float* ubase = U0 + (size_t)e * 4096 * 128 + d;
  float* ybase = Ysum + (size_t)e * 4096 * 128 + d;
  __syncthreads();
#pragma unroll 2
  for (int s = 0; s < NSTEPS; ++s) {
    float4 s4 = sDt[s];
    float xv = bd + w0 * s4.x + w1 * s4.y + w2 * s4.z + w3 * s4.w;
    float dlt = softplus_(xv);
    int p = ls0 + s;
    int r0 = rv ? (4095 - p) : p;
    int row = tq ? (((r0 & 63) << 6) | (r0 >> 6)) : r0;   // == output row
    float uu = ubase[(size_t)row * 128];
    float du = dlt * uu;
    float ya = 0.f, yb = 0.f, yc = 0.f, yd = 0.f;
#pragma unroll
    for (int n4 = 0; n4 < 4; ++n4) {
      float4 b4 = sB[s * 4 + n4];
      float4 c4 = sC[s * 4 + n4];
      h[n4*4+0] = fmaf(EXP2R(dlt * a2[n4*4+0]), h[n4*4+0], du * b4.x);
      h[n4*4+1] = fmaf(EXP2R(dlt * a2[n4*4+1]), h[n4*4+1], du * b4.y);
      h[n4*4+2] = fmaf(EXP2R(dlt * a2[n4*4+2]), h[n4*4+2], du * b4.z);
      h[n4*4+3] = fmaf(EXP2R(dlt * a2[n4*4+3]), h[n4*4+3], du * b4.w);
      ya = fmaf(h[n4*4+0], c4.x, ya);
      yb = fmaf(h[n4*4+1], c4.y, yb);
      yc = fmaf(h[n4*4+2], c4.z, yc);
      yd = fmaf(h[n4*4+3], c4.w, yd);
    }
    atomicAdd(ybase + (size_t)row * 128, (ya + yb) + (yc + yd));
  }
}

// ---------------- K7b: out_norm LN * silu(z) -> out_proj (opwF direct) -> +residual -> P ----------------
__global__ __launch_bounds__(256) void k7b_out(
    const float* __restrict__ Ysum, const float* __restrict__ T4,
    const float* __restrict__ T1,
    const void* ong, const void* onb, const float* __restrict__ opwF,
    const void* scale_p, const int* __restrict__ flag,
    float* __restrict__ P)
{
  bool isb = (*flag != 0);
  int bid = blockIdx.x; int e = bid >> 7, lt = bid & 127;
  int l0 = lt * 32;
  int t = threadIdx.x;
  __shared__ float sY[32][132];
  __shared__ float sMu[32], sRs[32];
  __shared__ float sPs[32][8], sPq[32][8];
  __shared__ float sP[64][33];
  for (int q = t; q < 1024; q += 256) {
    int l = q >> 5, d4 = (q & 31) * 4;
    float4 v = *(const float4*)(Ysum + ((size_t)e * 4096 + l0 + l) * 128 + d4);
    *(float4*)&sY[l][d4] = v;
  }
  __syncthreads();
  {
    int l = t & 31, g = t >> 5;
    float s = 0.f, q2 = 0.f;
#pragma unroll
    for (int j = 0; j < 16; ++j) { float v = sY[l][g * 16 + j]; s += v; q2 += v * v; }
    sPs[l][g] = s; sPq[l][g] = q2;
  }
  __syncthreads();
  if (t < 32) {
    float s = 0.f, q2 = 0.f;
#pragma unroll
    for (int g = 0; g < 8; ++g) { s += sPs[t][g]; q2 += sPq[t][g]; }
    float mu = s * (1.f / 128.f);
    float var = q2 * (1.f / 128.f) - mu * mu;
    sMu[t] = mu; sRs[t] = rsqrtf(var + 1e-5f);
  }
  __syncthreads();
  for (int idx = t; idx < 4096; idx += 256) {
    int l = idx >> 7, dd2 = idx & 127;
    float v = (sY[l][dd2] - sMu[l]) * sRs[l] * LD(ong, dd2, isb) + LD(onb, dd2, isb);
    v *= T4[((size_t)e * 4096 + l0 + l) * 128 + dd2];
    sY[l][dd2] = v;
  }
  __syncthreads();
  float ops = 1.f + LD(scale_p, 0, isb);
  {
    int l = t & 31, cg = t >> 5;
    const float4* wob = (const float4*)opwF;
    float acc[8];
#pragma unroll
    for (int j = 0; j < 8; ++j) acc[j] = 0.f;
    for (int dd = 0; dd < 32; ++dd) {
      float4 v4 = *(const float4*)&sY[l][dd * 4];
      float va[4] = {v4.x, v4.y, v4.z, v4.w};
#pragma unroll
      for (int j = 0; j < 8; ++j) {
        float4 w4 = wob[(cg * 8 + j) * 32 + dd];   // half-wave broadcast, L1-resident
        acc[j] += va[0] * w4.x + va[1] * w4.y + va[2] * w4.z + va[3] * w4.w;
      }
    }
#pragma unroll
    for (int j = 0; j < 8; ++j) {
      int c = cg * 8 + j;
      sP[c][l] = acc[j] + ops * T1[((size_t)e * 4096 + l0 + l) * 64 + c];
    }
  }
  __syncthreads();
  for (int q = t; q < 512; q += 256) {
    int c = q >> 3, lq = (q & 7) * 4;
    float4 o; o.x = sP[c][lq]; o.y = sP[c][lq+1]; o.z = sP[c][lq+2]; o.w = sP[c][lq+3];
    *(float4*)(P + ((size_t)e * 64 + c) * 4096 + l0 + lq) = o;
  }
}

// ---------------- K7c: instance-norm over L per (e,c) + leaky relu + out ----------------
__global__ __launch_bounds__(256) void k7c_final(
    const float* __restrict__ P, const void* gamma, const void* beta,
    const int* __restrict__ flag, void* __restrict__ out)
{
  bool isb = (*flag != 0);
  int bid = blockIdx.x; int e = bid >> 6, c = bid & 63;
  int b = e & 3, br = e >> 2;
  int cg = br * 64 + c;
  int t = threadIdx.x;
  const float* p = P + ((size_t)e * 64 + c) * 4096;
  float s = 0.f, q2 = 0.f;
  for (int q = t; q < 1024; q += 256) {
    float4 v = *(const float4*)(p + q * 4);
    s += v.x + v.y + v.z + v.w;
    q2 += v.x * v.x + v.y * v.y + v.z * v.z + v.w * v.w;
  }
#pragma unroll
  for (int off = 1; off < 64; off <<= 1) { s += __shfl_xor(s, off); q2 += __shfl_xor(q2, off); }
  __shared__ float rS[4], rQ[4];
  if ((t & 63) == 0) { rS[t >> 6] = s; rQ[t >> 6] = q2; }
  __syncthreads();
  float ts = rS[0] + rS[1] + rS[2] + rS[3];
  float tq = rQ[0] + rQ[1] + rQ[2] + rQ[3];
  float mu = ts * (1.f / 4096.f);
  float var = tq * (1.f / 4096.f) - mu * mu;
  float rsg = rsqrtf(var + 1e-5f);
  float gm = LD(gamma, cg, isb), bt = LD(beta, cg, isb);
  size_t obase = ((size_t)(b * 128 + cg)) * 4096;
  for (int q = t; q < 1024; q += 256) {
    float4 v = *(const float4*)(p + q * 4);
    float o0 = (v.x - mu) * rsg * gm + bt; o0 = o0 > 0.f ? o0 : 0.01f * o0;
    float o1 = (v.y - mu) * rsg * gm + bt; o1 = o1 > 0.f ? o1 : 0.01f * o1;
    float o2 = (v.z - mu) * rsg * gm + bt; o2 = o2 > 0.f ? o2 : 0.01f * o2;
    float o3 = (v.w - mu) * rsg * gm + bt; o3 = o3 > 0.f ? o3 : 0.01f * o3;
    if (isb) {
      unsigned short* op = (unsigned short*)out + obase;
      unsigned lo = (unsigned)f2bf(o0) | ((unsigned)f2bf(o1) << 16);
      unsigned hi = (unsigned)f2bf(o2) | ((unsigned)f2bf(o3) << 16);
      uint2 u; u.x = lo; u.y = hi;
      *(uint2*)(op + q * 4) = u;
    } else {
      float* op = (float*)out + obase;
      float4 o; o.x = o0; o.y = o1; o.z = o2; o.w = o3;
      *(float4*)(op + q * 4) = o;
    }
  }
}

extern "C" void kernel_launch(void* const* d_in, const int* in_sizes, int n_in,
                              void* d_out, int out_size, void* d_ws, size_t ws_size,
                              hipStream_t stream) {
  (void)in_sizes; (void)n_in; (void)out_size; (void)ws_size;
  const void* x      = d_in[0];
  const void* dw_w   = d_in[1];
  const void* dw_b   = d_in[2];
  const void* scale  = d_in[3];
  const void* ln1_g  = d_in[4];
  const void* ln1_b  = d_in[5];
  const void* ipw    = d_in[6];
  const void* conv_w = d_in[7];
  const void* conv_b = d_in[8];
  const void* xpw    = d_in[9];
  const void* dtw    = d_in[10];
  const void* dtb    = d_in[11];
  const void* alog   = d_in[12];
  const void* Ds     = d_in[13];
  const void* ong    = d_in[14];
  const void* onb    = d_in[15];
  const void* opw    = d_in[16];
  const void* ing    = d_in[17];
  const void* inb    = d_in[18];

  float* ws = (float*)d_ws;
  float* T1   = ws;                  // (E,L,64)  xd rows                    8.4MB
  float* T2   = ws + 2097152;        // (E,L,64)  xln -> dts4 -> P           8.4MB
  float* T3   = ws + 4194304;        // (E,L,128) conv-in -> Bb2+Cb2        16.8MB
  float* T4   = ws + 8388608;        // (E,L,128) silu(z)                   16.8MB
  float* U0   = ws + 12582912;       // (E,L,128) xc rows [h*64+w][d]       16.8MB
  float* Hsh  = ws + 16777216;       // 128 x (32ek x 128d x 16n) h-local   33.5MB
  float* Carry= ws + 25165824;       // same shape, exclusive carries       33.5MB
  float* Sdl  = ws + 33554432;       // 128 x (32ek x 128d) sdelta           2.1MB
  float* Ysum = ws + 34078720;       // (E,L,128) direction-merged y        16.8MB
  float* Bb2  = T3;                  // (EK,L,16)
  float* Cb2  = T3 + 2097152;        // (EK,L,16)
  float* dts4 = T2;                  // (EK,L,4) — overlays dead xln
  int* flag   = (int*)(ws + 38273024);
  float* a2tab= ws + 38273040;       // 8192
  float* xpwF = ws + 38281232;       // 18432 (K,36,128)
  float* opwF = ws + 38299664;       // 8192  (64,128)
  float* ipwF = ws + 38307856;       // 16384 (256,64); end ~153.3MB

  hipLaunchKernelGGL(kdet, dim3(1), dim3(64), 0, stream, x, flag);
  hipLaunchKernelGGL(kprep, dim3(72), dim3(256), 0, stream, alog, xpw, opw, ipw, flag, a2tab, xpwF, opwF, ipwF);
  hipLaunchKernelGGL(k0_conv_ln, dim3(512), dim3(256), 0, stream, x, dw_w, dw_b, ln1_g, ln1_b, flag, T1, T2);
  hipLaunchKernelGGL(k2_inproj, dim3(512, 4), dim3(256), 0, stream, T2, ipwF, T3, T4);
  hipLaunchKernelGGL(k3_conv2, dim3(512, 2), dim3(256), 0, stream, T3, conv_w, conv_b, Ds, flag, U0, Ysum);
  hipLaunchKernelGGL(k5_xdbl, dim3(64, 32), dim3(256), 0, stream, U0, xpwF, dts4, Bb2, Cb2);
  hipLaunchKernelGGL(k6a_chunk<32>, dim3(128, 32), dim3(128), 0, stream, U0, dts4, Bb2, a2tab, dtw, dtb, flag, Hsh, Sdl);
  hipLaunchKernelGGL(k6b_carry, dim3(256), dim3(256), 0, stream, Hsh, Sdl, a2tab, Carry);
  hipLaunchKernelGGL(k6c_apply<32>, dim3(128, 32), dim3(128), 0, stream, U0, Ysum, dts4, Bb2, Cb2, a2tab, dtw, dtb, Carry, flag);
  hipLaunchKernelGGL(k7b_out, dim3(1024), dim3(256), 0, stream, Ysum, T4, T1, ong, onb, opwF, scale, flag, T2);
  hipLaunchKernelGGL(k7c_final, dim3(512), dim3(256), 0, stream, T2, ing, inb, flag, d_out);
}

// Round 10
// 420.993 us; speedup vs baseline: 1.0953x; 1.0953x over previous
//
#include <hip/hip_runtime.h>
#include <hip/hip_bf16.h>

// MambaSplit: B=4,C=128,H=W=64, D=64, DI=128, N=16, R=4, K=4, L=4096, E=2*B=8
// Round-22: round-9 minus the k5 regression. k5's weight path reverted to LDS
// staging (inner-loop global broadcast loads at 3-4 blocks/CU were latency-
// bound: 83us, VALUBusy 29%) — but staged from the f32 xpwF table with plain
// float4 copies. k2 (ipwF) and k7b (direct opwF, 27KB LDS) kept from round 9
// (those netted ~-13us). k6 path untouched (67us, proven).

__device__ __forceinline__ float LD(const void* p, size_t i, bool isb) {
  if (isb) {
    unsigned short u = ((const unsigned short*)p)[i];
    return __uint_as_float(((unsigned)u) << 16);
  }
  return ((const float*)p)[i];
}
__device__ __forceinline__ unsigned short f2bf(float f) {
  unsigned u = __float_as_uint(f);
  u = (u + 0x7FFFu + ((u >> 16) & 1u)) >> 16;
  return (unsigned short)u;
}
__device__ __forceinline__ float silu_(float x) { return x / (1.f + __expf(-x)); }
__device__ __forceinline__ float softplus_(float x) {
  return x > 20.f ? x : __logf(1.f + __expf(x));
}
#define EXP2R(x) __builtin_amdgcn_exp2f(x)

// ---------------- detector: bf16 vs f32 input encoding ----------------
__global__ void kdet(const void* x, int* flag) {
  if (threadIdx.x == 0 && blockIdx.x == 0) {
    const unsigned short* xs = (const unsigned short*)x;
    int bad = 0;
    for (int i = 0; i < 64; ++i) {
      int e = (xs[2 * i] >> 7) & 0xFF;
      if (e > 150 || e < 100) bad++;
    }
    *flag = (bad >= 16) ? 0 : 1;
  }
}

// ---------------- KP: a2 table + f32 weight tables ----------------
__global__ __launch_bounds__(256) void kprep(
    const void* alog, const void* xpw, const void* opw, const void* ipw,
    const int* __restrict__ flag,
    float* __restrict__ a2tab, float* __restrict__ xpwF,
    float* __restrict__ opwF, float* __restrict__ ipwF)
{
  bool isb = (*flag != 0);
  int i = blockIdx.x * 256 + threadIdx.x;
  if (i < 8192)  a2tab[i] = -__expf(LD(alog, i, isb)) * 1.44269504f;
  if (i < 18432) xpwF[i] = LD(xpw, i, isb);   // (K,36,128)
  if (i < 8192)  opwF[i] = LD(opw, i, isb);   // (64,128)
  if (i < 16384) ipwF[i] = LD(ipw, i, isb);   // (256,64)
}

// ---------------- K0: dwconv(x) -> T1 (E,L,64) + LN -> T2 ----------------
__global__ __launch_bounds__(256) void k0_conv_ln(
    const void* x, const void* dww, const void* dwb, const void* lg, const void* lb,
    const int* __restrict__ flag,
    float* __restrict__ T1, float* __restrict__ T2)
{
  bool isb = (*flag != 0);
  int e = blockIdx.x >> 6, h = blockIdx.x & 63;
  int b = e & 3, br = e >> 2;
  int t = threadIdx.x;
  __shared__ float sIn[3][64][67];  // [row][d][1+w], w-halo zeroed
  for (int idx = t; idx < 3 * 64; idx += 256) {
    int r = idx >> 6, d = idx & 63;
    sIn[r][d][0] = 0.f; sIn[r][d][65] = 0.f;
  }
  for (int idx = t; idx < 3 * 64 * 64; idx += 256) {
    int r = idx >> 12, rem = idx & 4095, d = rem >> 6, w = rem & 63;
    int hh = h + r - 1;
    float v = 0.f;
    if (hh >= 0 && hh < 64) v = LD(x, ((size_t)(b * 128 + br * 64 + d) * 64 + hh) * 64 + w, isb);
    sIn[r][d][1 + w] = v;
  }
  __syncthreads();
  int w = t >> 2, g = t & 3;
  float vals[16]; float psum = 0.f, psq = 0.f;
#pragma unroll
  for (int j = 0; j < 16; ++j) {
    int d = g * 16 + j, c = br * 64 + d;
    float s = LD(dwb, c, isb);
#pragma unroll
    for (int kh = 0; kh < 3; ++kh)
#pragma unroll
      for (int kw = 0; kw < 3; ++kw)
        s += LD(dww, c * 9 + kh * 3 + kw, isb) * sIn[kh][d][w + kw];
    vals[j] = s; psum += s; psq += s * s;
  }
  size_t base = ((size_t)e * 4096 + h * 64) * 64 + (size_t)t * 16;
#pragma unroll
  for (int j4 = 0; j4 < 4; ++j4) {
    float4 o; o.x = vals[j4*4]; o.y = vals[j4*4+1]; o.z = vals[j4*4+2]; o.w = vals[j4*4+3];
    *(float4*)(T1 + base + j4 * 4) = o;
  }
  __shared__ float sS[64][4], sQ[64][4];
  sS[w][g] = psum; sQ[w][g] = psq;
  __syncthreads();
  float m = (sS[w][0] + sS[w][1] + sS[w][2] + sS[w][3]) * (1.f / 64.f);
  float q = (sQ[w][0] + sQ[w][1] + sQ[w][2] + sQ[w][3]) * (1.f / 64.f);
  float rs = rsqrtf(q - m * m + 1e-5f);
#pragma unroll
  for (int j4 = 0; j4 < 4; ++j4) {
    float tmp[4];
#pragma unroll
    for (int jj = 0; jj < 4; ++jj) {
      int j = j4 * 4 + jj; int d = g * 16 + j;
      tmp[jj] = (vals[j] - m) * rs * LD(lg, d, isb) + LD(lb, d, isb);
    }
    float4 o; o.x = tmp[0]; o.y = tmp[1]; o.z = tmp[2]; o.w = tmp[3];
    *(float4*)(T2 + base + j4 * 4) = o;
  }
}

// ---------------- K2: in_proj GEMM  T2(32768,64) @ W^T(64,256) -> T3 / T4 ----------------
__global__ __launch_bounds__(256) void k2_inproj(
    const float* __restrict__ T2, const float* __restrict__ ipwF,
    float* __restrict__ T3, float* __restrict__ T4)
{
  int mt = blockIdx.x, ct = blockIdx.y;
  int t = threadIdx.x;
  __shared__ float sA[64][68];  // [d][l]
  __shared__ float sB[64][68];  // [d][c]
  int row0 = mt * 64;
  for (int q = t; q < 1024; q += 256) {
    int l = q >> 4, d4 = (q & 15) * 4;
    float4 v = *(const float4*)(T2 + (size_t)(row0 + l) * 64 + d4);
    sA[d4][l] = v.x; sA[d4+1][l] = v.y; sA[d4+2][l] = v.z; sA[d4+3][l] = v.w;
  }
  for (int q = t; q < 1024; q += 256) {
    int cl = q >> 4, d4 = (q & 15) * 4;
    float4 v = *(const float4*)(ipwF + (size_t)(ct * 64 + cl) * 64 + d4);
    sB[d4][cl] = v.x; sB[d4+1][cl] = v.y; sB[d4+2][cl] = v.z; sB[d4+3][cl] = v.w;
  }
  __syncthreads();
  int ty = t >> 4, tx = t & 15;
  float acc[4][4];
#pragma unroll
  for (int i = 0; i < 4; ++i)
#pragma unroll
    for (int j = 0; j < 4; ++j) acc[i][j] = 0.f;
  for (int kk = 0; kk < 64; ++kk) {
    float4 a = *(const float4*)&sA[kk][ty * 4];
    float4 bq = *(const float4*)&sB[kk][tx * 4];
    float aa[4] = {a.x, a.y, a.z, a.w}, bb[4] = {bq.x, bq.y, bq.z, bq.w};
#pragma unroll
    for (int i = 0; i < 4; ++i)
#pragma unroll
      for (int j = 0; j < 4; ++j) acc[i][j] += aa[i] * bb[j];
  }
  int c0 = ct * 64 + tx * 4;
#pragma unroll
  for (int i = 0; i < 4; ++i) {
    size_t row = (size_t)row0 + ty * 4 + i;
    float4 o;
    if (c0 < 128) {
      o.x = acc[i][0]; o.y = acc[i][1]; o.z = acc[i][2]; o.w = acc[i][3];
      *(float4*)(T3 + row * 128 + c0) = o;
    } else {
      o.x = silu_(acc[i][0]); o.y = silu_(acc[i][1]); o.z = silu_(acc[i][2]); o.w = silu_(acc[i][3]);
      *(float4*)(T4 + row * 128 + (c0 - 128)) = o;
    }
  }
}

// ---------------- K3: depthwise conv 3x3 + SiLU -> U0, and Ysum = sumDs*u ----------------
__global__ __launch_bounds__(256) void k3_conv2(
    const float* __restrict__ T3, const void* cw, const void* cb, const void* Ds,
    const int* __restrict__ flag,
    float* __restrict__ U0, float* __restrict__ Ysum)
{
  bool isb = (*flag != 0);
  int e = blockIdx.x >> 6, h = blockIdx.x & 63, dc = blockIdx.y;
  int t = threadIdx.x;
  __shared__ float sI[3][66][65];  // [row][1+w][d]
  for (int idx = t; idx < 3 * 2 * 64; idx += 256) {
    int r = idx / 128, rem = idx % 128, side = rem >> 6, d = rem & 63;
    sI[r][side * 65][d] = 0.f;
  }
  for (int idx = t; idx < 3 * 64 * 64; idx += 256) {
    int r = idx >> 12, rem = idx & 4095, w = rem >> 6, d = rem & 63;
    int hh = h + r - 1;
    float v = 0.f;
    if (hh >= 0 && hh < 64) v = T3[((size_t)e * 4096 + hh * 64 + w) * 128 + dc * 64 + d];
    sI[r][1 + w][d] = v;
  }
  __syncthreads();
  int d = t & 63, wq = t >> 6;
  int c2 = dc * 64 + d;
  float wt[9];
#pragma unroll
  for (int m = 0; m < 9; ++m) wt[m] = LD(cw, c2 * 9 + m, isb);
  float bias = LD(cb, c2, isb);
  float sd = LD(Ds, c2, isb) + LD(Ds, 128 + c2, isb) + LD(Ds, 256 + c2, isb) + LD(Ds, 384 + c2, isb);
  size_t eb = (size_t)e * 4096;
#pragma unroll
  for (int i = 0; i < 16; ++i) {
    int w = wq * 16 + i;
    float s = bias;
#pragma unroll
    for (int kh = 0; kh < 3; ++kh)
#pragma unroll
      for (int kw = 0; kw < 3; ++kw)
        s += wt[kh * 3 + kw] * sI[kh][w + kw][d];
    s = silu_(s);
    U0[(eb + h * 64 + w) * 128 + c2] = s;
    Ysum[(eb + h * 64 + w) * 128 + c2] = sd * s;
  }
}

// ---------------- K5: x_dbl einsum -> dts4/Bb2/Cb2; sW staged in LDS from xpwF ----------------
__global__ __launch_bounds__(256) void k5_xdbl(
    const float* __restrict__ U0,
    const float* __restrict__ xpwF,
    float* __restrict__ dts4, float* __restrict__ Bb2, float* __restrict__ Cb2)
{
  int lt = blockIdx.x;   // 64 tiles of 64 along L
  int ek = blockIdx.y;   // e*4+k
  int e = ek >> 2, k = ek & 3;
  int ls0 = lt * 64;
  int t = threadIdx.x;
  __shared__ float sU[64][132];   // [l][d]
  __shared__ float sW[36][132];   // [c][d]
  for (int q = t; q < 1152; q += 256) {
    int c = q >> 5, d4 = (q & 31) * 4;
    float4 v = *(const float4*)(xpwF + ((size_t)k * 36 + c) * 128 + d4);
    *(float4*)&sW[c][d4] = v;
  }
  const bool rev = (k >= 2);
  const int trq = (k & 1);
  for (int idx = t; idx < 2048; idx += 256) {
    int l = idx >> 5, d4 = (idx & 31) * 4;
    int p = rev ? (4095 - ls0 - l) : (ls0 + l);
    int row = trq ? (((p & 63) << 6) | (p >> 6)) : p;
    float4 v = *(const float4*)(U0 + ((size_t)e * 4096 + row) * 128 + d4);
    *(float4*)&sU[l][d4] = v;
  }
  __syncthreads();
  int l = t & 63, cg = t >> 6;
  float acc[9];
#pragma unroll
  for (int j = 0; j < 9; ++j) acc[j] = 0.f;
  for (int dd = 0; dd < 32; ++dd) {
    float4 u4 = *(const float4*)&sU[l][dd * 4];
    float ua[4] = {u4.x, u4.y, u4.z, u4.w};
#pragma unroll
    for (int j = 0; j < 9; ++j) {
      float4 w4 = *(const float4*)&sW[cg * 9 + j][dd * 4];
      acc[j] += ua[0] * w4.x + ua[1] * w4.y + ua[2] * w4.z + ua[3] * w4.w;
    }
  }
  size_t row = (size_t)ek * 4096 + ls0 + l;
  if (cg == 0) {
    float4 o; o.x = acc[0]; o.y = acc[1]; o.z = acc[2]; o.w = acc[3];
    *(float4*)(dts4 + row * 4) = o;
#pragma unroll
    for (int j = 4; j < 9; ++j) Bb2[row * 16 + (j - 4)] = acc[j];
  } else {
#pragma unroll
    for (int j = 0; j < 9; ++j) {
      int c = cg * 9 + j;
      if (c < 20) Bb2[row * 16 + (c - 4)] = acc[j];
      else Cb2[row * 16 + (c - 20)] = acc[j];
    }
  }
}

// ---------------- K6a: chunk-local scan, LDS-staged dts4/B -> Hsh + Sdl ----------------
template<int NSTEPS>
__global__ __launch_bounds__(128) void k6a_chunk(
    const float* __restrict__ U0,
    const float* __restrict__ dts4, const float* __restrict__ Bb2,
    const float* __restrict__ a2tab, const void* dtw, const void* dtb,
    const int* __restrict__ flag,
    float* __restrict__ Hsh, float* __restrict__ Sdl)
{
  bool isb = (*flag != 0);
  int chunk = blockIdx.x, ek = blockIdx.y;
  int e = ek >> 2, k = ek & 3;
  int d = threadIdx.x;
  int ls0 = chunk * NSTEPS;
  __shared__ float4 sDt[NSTEPS];        // 512B
  __shared__ float4 sB[NSTEPS * 4];     // 2KB
  {
    const float4* srcd = (const float4*)(dts4 + ((size_t)ek * 4096 + ls0) * 4);
    const float4* srcb = (const float4*)(Bb2 + ((size_t)ek * 4096 + ls0) * 16);
    if (d < NSTEPS) sDt[d] = srcd[d];
    sB[d] = srcb[d];
  }
  float a2[16];
  {
    const float4* ap = (const float4*)(a2tab + ((size_t)k * 128 + d) * 16);
#pragma unroll
    for (int n4 = 0; n4 < 4; ++n4) {
      float4 v = ap[n4];
      a2[n4*4+0] = v.x; a2[n4*4+1] = v.y; a2[n4*4+2] = v.z; a2[n4*4+3] = v.w;
    }
  }
  float w0 = LD(dtw, ((size_t)k * 128 + d) * 4 + 0, isb);
  float w1 = LD(dtw, ((size_t)k * 128 + d) * 4 + 1, isb);
  float w2 = LD(dtw, ((size_t)k * 128 + d) * 4 + 2, isb);
  float w3 = LD(dtw, ((size_t)k * 128 + d) * 4 + 3, isb);
  float bd = LD(dtb, k * 128 + d, isb);
  float h[16];
#pragma unroll
  for (int n = 0; n < 16; ++n) h[n] = 0.f;
  float sdelta = 0.f;
  const bool rv = (k >= 2);
  const int tq = (k & 1);
  const float* ubase = U0 + (size_t)e * 4096 * 128 + d;
  __syncthreads();
#pragma unroll 2
  for (int s = 0; s < NSTEPS; ++s) {
    float4 s4 = sDt[s];
    float xv = bd + w0 * s4.x + w1 * s4.y + w2 * s4.z + w3 * s4.w;
    float dlt = softplus_(xv);
    int p = ls0 + s;
    int r0 = rv ? (4095 - p) : p;
    int row = tq ? (((r0 & 63) << 6) | (r0 >> 6)) : r0;
    float uu = ubase[(size_t)row * 128];
    float du = dlt * uu;
    sdelta += dlt;
#pragma unroll
    for (int n4 = 0; n4 < 4; ++n4) {
      float4 b4 = sB[s * 4 + n4];
      h[n4*4+0] = fmaf(EXP2R(dlt * a2[n4*4+0]), h[n4*4+0], du * b4.x);
      h[n4*4+1] = fmaf(EXP2R(dlt * a2[n4*4+1]), h[n4*4+1], du * b4.y);
      h[n4*4+2] = fmaf(EXP2R(dlt * a2[n4*4+2]), h[n4*4+2], du * b4.z);
      h[n4*4+3] = fmaf(EXP2R(dlt * a2[n4*4+3]), h[n4*4+3], du * b4.w);
    }
  }
  float* hp = Hsh + (size_t)chunk * 65536 + (size_t)ek * 2048 + (size_t)d * 16;
#pragma unroll
  for (int n4 = 0; n4 < 4; ++n4) {
    float4 o; o.x = h[n4*4]; o.y = h[n4*4+1]; o.z = h[n4*4+2]; o.w = h[n4*4+3];
    *(float4*)(hp + n4 * 4) = o;
  }
  Sdl[(size_t)chunk * 4096 + ek * 128 + d] = sdelta;
}

// ---------------- K6b: carry scan; prodA recomputed from sdelta; exclusive Carry out ----------------
__global__ __launch_bounds__(256) void k6b_carry(
    const float* __restrict__ Hsh, const float* __restrict__ Sdl,
    const float* __restrict__ a2tab,
    float* __restrict__ Carry)
{
  int idx = blockIdx.x * 256 + threadIdx.x;   // 65536 = ek*2048 + d*16 + n
  int ek = idx >> 11;
  int k = ek & 3;
  float a2 = a2tab[(size_t)k * 2048 + (idx & 2047)];
  int sidx = ek * 128 + ((idx & 2047) >> 4);
  float carry = 0.f;
  for (int c0 = 0; c0 < 128; c0 += 8) {
    float hv[8], pA[8];
#pragma unroll
    for (int j = 0; j < 8; ++j) {
      hv[j] = Hsh[(size_t)(c0 + j) * 65536 + idx];
      pA[j] = Sdl[(size_t)(c0 + j) * 4096 + sidx];
    }
#pragma unroll
    for (int j = 0; j < 8; ++j) pA[j] = EXP2R(a2 * pA[j]);
#pragma unroll
    for (int j = 0; j < 8; ++j) {
      Carry[(size_t)(c0 + j) * 65536 + idx] = carry;   // exclusive prefix
      carry = fmaf(pA[j], carry, hv[j]);
    }
  }
}

// ---------------- K6c: seeded chunk scan, LDS-staged dts4/B/C; atomic y-merge ----------------
// u-read row == output row for every direction k (reversal+transpose fold).
template<int NSTEPS>
__global__ __launch_bounds__(128) void k6c_apply(
    const float* __restrict__ U0,
    float* __restrict__ Ysum, const float* __restrict__ dts4,
    const float* __restrict__ Bb2, const float* __restrict__ Cb2,
    const float* __restrict__ a2tab, const void* dtw, const void* dtb,
    const float* __restrict__ Carry, const int* __restrict__ flag)
{
  bool isb = (*flag != 0);
  int chunk = blockIdx.x, ek = blockIdx.y;
  int e = ek >> 2, k = ek & 3;
  int d = threadIdx.x;
  int ls0 = chunk * NSTEPS;
  __shared__ float4 sDt[NSTEPS];        // 512B
  __shared__ float4 sB[NSTEPS * 4];     // 2KB
  __shared__ float4 sC[NSTEPS * 4];     // 2KB
  {
    const float4* srcd = (const float4*)(dts4 + ((size_t)ek * 4096 + ls0) * 4);
    const float4* srcb = (const float4*)(Bb2 + ((size_t)ek * 4096 + ls0) * 16);
    const float4* srcc = (const float4*)(Cb2 + ((size_t)ek * 4096 + ls0) * 16);
    if (d < NSTEPS) sDt[d] = srcd[d];
    sB[d] = srcb[d];
    sC[d] = srcc[d];
  }
  float a2[16];
  {
    const float4* ap = (const float4*)(a2tab + ((size_t)k * 128 + d) * 16);
#pragma unroll
    for (int n4 = 0; n4 < 4; ++n4) {
      float4 v = ap[n4];
      a2[n4*4+0] = v.x; a2[n4*4+1] = v.y; a2[n4*4+2] = v.z; a2[n4*4+3] = v.w;
    }
  }
  float w0 = LD(dtw, ((size_t)k * 128 + d) * 4 + 0, isb);
  float w1 = LD(dtw, ((size_t)k * 128 + d) * 4 + 1, isb);
  float w2 = LD(dtw, ((size_t)k * 128 + d) * 4 + 2, isb);
  float w3 = LD(dtw, ((size_t)k * 128 + d) * 4 + 3, isb);
  float bd = LD(dtb, k * 128 + d, isb);
  float h[16];
  {
    const float* cp = Carry + (size_t)chunk * 65536 + (size_t)ek * 2048 + (size_t)d * 16;
#pragma unroll
    for (int n = 0; n < 16; ++n) h[n] = cp[n];
  }
  const bool rv = (k >= 2);
  const int tq = (k & 1);
  const float* ubase = U0 + (size_t)e * 4096 * 128 + d;
  float* ybase = Ysum + (size_t)e * 4096 * 128 + d;
  __syncthreads();
#pragma unroll 2
  for (int s = 0; s < NSTEPS; ++s) {
    float4 s4 = sDt[s];
    float xv = bd + w0 * s4.x + w1 * s4.y + w2 * s4.z + w3 * s4.w;
    float dlt = softplus_(xv);
    int p = ls0 + s;
    int r0 = rv ? (4095 - p) : p;
    int row = tq ? (((r0 & 63) << 6) | (r0 >> 6)) : r0;   // == output row
    float uu = ubase[(size_t)row * 128];
    float du = dlt * uu;
    float ya = 0.f, yb = 0.f, yc = 0.f, yd = 0.f;
#pragma unroll
    for (int n4 = 0; n4 < 4; ++n4) {
      float4 b4 = sB[s * 4 + n4];
      float4 c4 = sC[s * 4 + n4];
      h[n4*4+0] = fmaf(EXP2R(dlt * a2[n4*4+0]), h[n4*4+0], du * b4.x);
      h[n4*4+1] = fmaf(EXP2R(dlt * a2[n4*4+1]), h[n4*4+1], du * b4.y);
      h[n4*4+2] = fmaf(EXP2R(dlt * a2[n4*4+2]), h[n4*4+2], du * b4.z);
      h[n4*4+3] = fmaf(EXP2R(dlt * a2[n4*4+3]), h[n4*4+3], du * b4.w);
      ya = fmaf(h[n4*4+0], c4.x, ya);
      yb = fmaf(h[n4*4+1], c4.y, yb);
      yc = fmaf(h[n4*4+2], c4.z, yc);
      yd = fmaf(h[n4*4+3], c4.w, yd);
    }
    atomicAdd(ybase + (size_t)row * 128, (ya + yb) + (yc + yd));
  }
}

// ---------------- K7b: out_norm LN * silu(z) -> out_proj (opwF direct) -> +residual -> P ----------------
__global__ __launch_bounds__(256) void k7b_out(
    const float* __restrict__ Ysum, const float* __restrict__ T4,
    const float* __restrict__ T1,
    const void* ong, const void* onb, const float* __restrict__ opwF,
    const void* scale_p, const int* __restrict__ flag,
    float* __restrict__ P)
{
  bool isb = (*flag != 0);
  int bid = blockIdx.x; int e = bid >> 7, lt = bid & 127;
  int l0 = lt * 32;
  int t = threadIdx.x;
  __shared__ float sY[32][132];
  __shared__ float sMu[32], sRs[32];
  __shared__ float sPs[32][8], sPq[32][8];
  __shared__ float sP[64][33];
  for (int q = t; q < 1024; q += 256) {
    int l = q >> 5, d4 = (q & 31) * 4;
    float4 v = *(const float4*)(Ysum + ((size_t)e * 4096 + l0 + l) * 128 + d4);
    *(float4*)&sY[l][d4] = v;
  }
  __syncthreads();
  {
    int l = t & 31, g = t >> 5;
    float s = 0.f, q2 = 0.f;
#pragma unroll
    for (int j = 0; j < 16; ++j) { float v = sY[l][g * 16 + j]; s += v; q2 += v * v; }
    sPs[l][g] = s; sPq[l][g] = q2;
  }
  __syncthreads();
  if (t < 32) {
    float s = 0.f, q2 = 0.f;
#pragma unroll
    for (int g = 0; g < 8; ++g) { s += sPs[t][g]; q2 += sPq[t][g]; }
    float mu = s * (1.f / 128.f);
    float var = q2 * (1.f / 128.f) - mu * mu;
    sMu[t] = mu; sRs[t] = rsqrtf(var + 1e-5f);
  }
  __syncthreads();
  for (int idx = t; idx < 4096; idx += 256) {
    int l = idx >> 7, dd2 = idx & 127;
    float v = (sY[l][dd2] - sMu[l]) * sRs[l] * LD(ong, dd2, isb) + LD(onb, dd2, isb);
    v *= T4[((size_t)e * 4096 + l0 + l) * 128 + dd2];
    sY[l][dd2] = v;
  }
  __syncthreads();
  float ops = 1.f + LD(scale_p, 0, isb);
  {
    int l = t & 31, cg = t >> 5;
    const float4* wob = (const float4*)opwF;
    float acc[8];
#pragma unroll
    for (int j = 0; j < 8; ++j) acc[j] = 0.f;
    for (int dd = 0; dd < 32; ++dd) {
      float4 v4 = *(const float4*)&sY[l][dd * 4];
      float va[4] = {v4.x, v4.y, v4.z, v4.w};
#pragma unroll
      for (int j = 0; j < 8; ++j) {
        float4 w4 = wob[(cg * 8 + j) * 32 + dd];   // half-wave broadcast, L1-resident
        acc[j] += va[0] * w4.x + va[1] * w4.y + va[2] * w4.z + va[3] * w4.w;
      }
    }
#pragma unroll
    for (int j = 0; j < 8; ++j) {
      int c = cg * 8 + j;
      sP[c][l] = acc[j] + ops * T1[((size_t)e * 4096 + l0 + l) * 64 + c];
    }
  }
  __syncthreads();
  for (int q = t; q < 512; q += 256) {
    int c = q >> 3, lq = (q & 7) * 4;
    float4 o; o.x = sP[c][lq]; o.y = sP[c][lq+1]; o.z = sP[c][lq+2]; o.w = sP[c][lq+3];
    *(float4*)(P + ((size_t)e * 64 + c) * 4096 + l0 + lq) = o;
  }
}

// ---------------- K7c: instance-norm over L per (e,c) + leaky relu + out ----------------
__global__ __launch_bounds__(256) void k7c_final(
    const float* __restrict__ P, const void* gamma, const void* beta,
    const int* __restrict__ flag, void* __restrict__ out)
{
  bool isb = (*flag != 0);
  int bid = blockIdx.x; int e = bid >> 6, c = bid & 63;
  int b = e & 3, br = e >> 2;
  int cg = br * 64 + c;
  int t = threadIdx.x;
  const float* p = P + ((size_t)e * 64 + c) * 4096;
  float s = 0.f, q2 = 0.f;
  for (int q = t; q < 1024; q += 256) {
    float4 v = *(const float4*)(p + q * 4);
    s += v.x + v.y + v.z + v.w;
    q2 += v.x * v.x + v.y * v.y + v.z * v.z + v.w * v.w;
  }
#pragma unroll
  for (int off = 1; off < 64; off <<= 1) { s += __shfl_xor(s, off); q2 += __shfl_xor(q2, off); }
  __shared__ float rS[4], rQ[4];
  if ((t & 63) == 0) { rS[t >> 6] = s; rQ[t >> 6] = q2; }
  __syncthreads();
  float ts = rS[0] + rS[1] + rS[2] + rS[3];
  float tq = rQ[0] + rQ[1] + rQ[2] + rQ[3];
  float mu = ts * (1.f / 4096.f);
  float var = tq * (1.f / 4096.f) - mu * mu;
  float rsg = rsqrtf(var + 1e-5f);
  float gm = LD(gamma, cg, isb), bt = LD(beta, cg, isb);
  size_t obase = ((size_t)(b * 128 + cg)) * 4096;
  for (int q = t; q < 1024; q += 256) {
    float4 v = *(const float4*)(p + q * 4);
    float o0 = (v.x - mu) * rsg * gm + bt; o0 = o0 > 0.f ? o0 : 0.01f * o0;
    float o1 = (v.y - mu) * rsg * gm + bt; o1 = o1 > 0.f ? o1 : 0.01f * o1;
    float o2 = (v.z - mu) * rsg * gm + bt; o2 = o2 > 0.f ? o2 : 0.01f * o2;
    float o3 = (v.w - mu) * rsg * gm + bt; o3 = o3 > 0.f ? o3 : 0.01f * o3;
    if (isb) {
      unsigned short* op = (unsigned short*)out + obase;
      unsigned lo = (unsigned)f2bf(o0) | ((unsigned)f2bf(o1) << 16);
      unsigned hi = (unsigned)f2bf(o2) | ((unsigned)f2bf(o3) << 16);
      uint2 u; u.x = lo; u.y = hi;
      *(uint2*)(op + q * 4) = u;
    } else {
      float* op = (float*)out + obase;
      float4 o; o.x = o0; o.y = o1; o.z = o2; o.w = o3;
      *(float4*)(op + q * 4) = o;
    }
  }
}

extern "C" void kernel_launch(void* const* d_in, const int* in_sizes, int n_in,
                              void* d_out, int out_size, void* d_ws, size_t ws_size,
                              hipStream_t stream) {
  (void)in_sizes; (void)n_in; (void)out_size; (void)ws_size;
  const void* x      = d_in[0];
  const void* dw_w   = d_in[1];
  const void* dw_b   = d_in[2];
  const void* scale  = d_in[3];
  const void* ln1_g  = d_in[4];
  const void* ln1_b  = d_in[5];
  const void* ipw    = d_in[6];
  const void* conv_w = d_in[7];
  const void* conv_b = d_in[8];
  const void* xpw    = d_in[9];
  const void* dtw    = d_in[10];
  const void* dtb    = d_in[11];
  const void* alog   = d_in[12];
  const void* Ds     = d_in[13];
  const void* ong    = d_in[14];
  const void* onb    = d_in[15];
  const void* opw    = d_in[16];
  const void* ing    = d_in[17];
  const void* inb    = d_in[18];

  float* ws = (float*)d_ws;
  float* T1   = ws;                  // (E,L,64)  xd rows                    8.4MB
  float* T2   = ws + 2097152;        // (E,L,64)  xln -> dts4 -> P           8.4MB
  float* T3   = ws + 4194304;        // (E,L,128) conv-in -> Bb2+Cb2        16.8MB
  float* T4   = ws + 8388608;        // (E,L,128) silu(z)                   16.8MB
  float* U0   = ws + 12582912;       // (E,L,128) xc rows [h*64+w][d]       16.8MB
  float* Hsh  = ws + 16777216;       // 128 x (32ek x 128d x 16n) h-local   33.5MB
  float* Carry= ws + 25165824;       // same shape, exclusive carries       33.5MB
  float* Sdl  = ws + 33554432;       // 128 x (32ek x 128d) sdelta           2.1MB
  float* Ysum = ws + 34078720;       // (E,L,128) direction-merged y        16.8MB
  float* Bb2  = T3;                  // (EK,L,16)
  float* Cb2  = T3 + 2097152;        // (EK,L,16)
  float* dts4 = T2;                  // (EK,L,4) — overlays dead xln
  int* flag   = (int*)(ws + 38273024);
  float* a2tab= ws + 38273040;       // 8192
  float* xpwF = ws + 38281232;       // 18432 (K,36,128)
  float* opwF = ws + 38299664;       // 8192  (64,128)
  float* ipwF = ws + 38307856;       // 16384 (256,64); end ~153.3MB

  hipLaunchKernelGGL(kdet, dim3(1), dim3(64), 0, stream, x, flag);
  hipLaunchKernelGGL(kprep, dim3(72), dim3(256), 0, stream, alog, xpw, opw, ipw, flag, a2tab, xpwF, opwF, ipwF);
  hipLaunchKernelGGL(k0_conv_ln, dim3(512), dim3(256), 0, stream, x, dw_w, dw_b, ln1_g, ln1_b, flag, T1, T2);
  hipLaunchKernelGGL(k2_inproj, dim3(512, 4), dim3(256), 0, stream, T2, ipwF, T3, T4);
  hipLaunchKernelGGL(k3_conv2, dim3(512, 2), dim3(256), 0, stream, T3, conv_w, conv_b, Ds, flag, U0, Ysum);
  hipLaunchKernelGGL(k5_xdbl, dim3(64, 32), dim3(256), 0, stream, U0, xpwF, dts4, Bb2, Cb2);
  hipLaunchKernelGGL(k6a_chunk<32>, dim3(128, 32), dim3(128), 0, stream, U0, dts4, Bb2, a2tab, dtw, dtb, flag, Hsh, Sdl);
  hipLaunchKernelGGL(k6b_carry, dim3(256), dim3(256), 0, stream, Hsh, Sdl, a2tab, Carry);
  hipLaunchKernelGGL(k6c_apply<32>, dim3(128, 32), dim3(128), 0, stream, U0, Ysum, dts4, Bb2, Cb2, a2tab, dtw, dtb, Carry, flag);
  hipLaunchKernelGGL(k7b_out, dim3(1024), dim3(256), 0, stream, Ysum, T4, T1, ong, onb, opwF, scale, flag, T2);
  hipLaunchKernelGGL(k7c_final, dim3(512), dim3(256), 0, stream, T2, ing, inb, flag, d_out);
}

// Round 11
// 408.143 us; speedup vs baseline: 1.1298x; 1.0315x over previous
//
#include <hip/hip_runtime.h>
#include <hip/hip_bf16.h>

// MambaSplit: B=4,C=128,H=W=64, D=64, DI=128, N=16, R=4, K=4, L=4096, E=2*B=8
// Round-23: round-10 (421us best) + bf16-compressed LDS staging in the three
// occupancy-capped stencil/einsum kernels: k0 sIn 51.5->25.7KB (3->5 blk/CU),
// k3 sI 51.5->25.7KB (3->6 blk/CU), k5 sU 33.8->16.9KB + sW pad dropped
// (52.8->35.3KB, 3->4 blk/CU). Unpack = 1 VALU op/element; precision headroom
// 6x (absmax 0.0156 vs 0.0956). k6 path byte-identical (67us proven).

__device__ __forceinline__ float LD(const void* p, size_t i, bool isb) {
  if (isb) {
    unsigned short u = ((const unsigned short*)p)[i];
    return __uint_as_float(((unsigned)u) << 16);
  }
  return ((const float*)p)[i];
}
__device__ __forceinline__ unsigned short f2bf(float f) {
  unsigned u = __float_as_uint(f);
  u = (u + 0x7FFFu + ((u >> 16) & 1u)) >> 16;
  return (unsigned short)u;
}
__device__ __forceinline__ float b2f(unsigned short u) {
  return __uint_as_float(((unsigned)u) << 16);
}
__device__ __forceinline__ float silu_(float x) { return x / (1.f + __expf(-x)); }
__device__ __forceinline__ float softplus_(float x) {
  return x > 20.f ? x : __logf(1.f + __expf(x));
}
#define EXP2R(x) __builtin_amdgcn_exp2f(x)

// ---------------- detector: bf16 vs f32 input encoding ----------------
__global__ void kdet(const void* x, int* flag) {
  if (threadIdx.x == 0 && blockIdx.x == 0) {
    const unsigned short* xs = (const unsigned short*)x;
    int bad = 0;
    for (int i = 0; i < 64; ++i) {
      int e = (xs[2 * i] >> 7) & 0xFF;
      if (e > 150 || e < 100) bad++;
    }
    *flag = (bad >= 16) ? 0 : 1;
  }
}

// ---------------- KP: a2 table + f32 weight tables ----------------
__global__ __launch_bounds__(256) void kprep(
    const void* alog, const void* xpw, const void* opw, const void* ipw,
    const int* __restrict__ flag,
    float* __restrict__ a2tab, float* __restrict__ xpwF,
    float* __restrict__ opwF, float* __restrict__ ipwF)
{
  bool isb = (*flag != 0);
  int i = blockIdx.x * 256 + threadIdx.x;
  if (i < 8192)  a2tab[i] = -__expf(LD(alog, i, isb)) * 1.44269504f;
  if (i < 18432) xpwF[i] = LD(xpw, i, isb);   // (K,36,128)
  if (i < 8192)  opwF[i] = LD(opw, i, isb);   // (64,128)
  if (i < 16384) ipwF[i] = LD(ipw, i, isb);   // (256,64)
}

// ---------------- K0: dwconv(x) -> T1 (E,L,64) + LN -> T2 (bf16 LDS staging) ----------------
__global__ __launch_bounds__(256) void k0_conv_ln(
    const void* x, const void* dww, const void* dwb, const void* lg, const void* lb,
    const int* __restrict__ flag,
    float* __restrict__ T1, float* __restrict__ T2)
{
  bool isb = (*flag != 0);
  int e = blockIdx.x >> 6, h = blockIdx.x & 63;
  int b = e & 3, br = e >> 2;
  int t = threadIdx.x;
  __shared__ unsigned short sIn[3][64][67];  // bf16: [row][d][1+w], 25.7KB
  for (int idx = t; idx < 3 * 64; idx += 256) {
    int r = idx >> 6, d = idx & 63;
    sIn[r][d][0] = 0; sIn[r][d][65] = 0;
  }
  for (int idx = t; idx < 3 * 64 * 64; idx += 256) {
    int r = idx >> 12, rem = idx & 4095, d = rem >> 6, w = rem & 63;
    int hh = h + r - 1;
    float v = 0.f;
    if (hh >= 0 && hh < 64) v = LD(x, ((size_t)(b * 128 + br * 64 + d) * 64 + hh) * 64 + w, isb);
    sIn[r][d][1 + w] = f2bf(v);
  }
  __syncthreads();
  int w = t >> 2, g = t & 3;
  float vals[16]; float psum = 0.f, psq = 0.f;
#pragma unroll
  for (int j = 0; j < 16; ++j) {
    int d = g * 16 + j, c = br * 64 + d;
    float s = LD(dwb, c, isb);
#pragma unroll
    for (int kh = 0; kh < 3; ++kh)
#pragma unroll
      for (int kw = 0; kw < 3; ++kw)
        s += LD(dww, c * 9 + kh * 3 + kw, isb) * b2f(sIn[kh][d][w + kw]);
    vals[j] = s; psum += s; psq += s * s;
  }
  size_t base = ((size_t)e * 4096 + h * 64) * 64 + (size_t)t * 16;
#pragma unroll
  for (int j4 = 0; j4 < 4; ++j4) {
    float4 o; o.x = vals[j4*4]; o.y = vals[j4*4+1]; o.z = vals[j4*4+2]; o.w = vals[j4*4+3];
    *(float4*)(T1 + base + j4 * 4) = o;
  }
  __shared__ float sS[64][4], sQ[64][4];
  sS[w][g] = psum; sQ[w][g] = psq;
  __syncthreads();
  float m = (sS[w][0] + sS[w][1] + sS[w][2] + sS[w][3]) * (1.f / 64.f);
  float q = (sQ[w][0] + sQ[w][1] + sQ[w][2] + sQ[w][3]) * (1.f / 64.f);
  float rs = rsqrtf(q - m * m + 1e-5f);
#pragma unroll
  for (int j4 = 0; j4 < 4; ++j4) {
    float tmp[4];
#pragma unroll
    for (int jj = 0; jj < 4; ++jj) {
      int j = j4 * 4 + jj; int d = g * 16 + j;
      tmp[jj] = (vals[j] - m) * rs * LD(lg, d, isb) + LD(lb, d, isb);
    }
    float4 o; o.x = tmp[0]; o.y = tmp[1]; o.z = tmp[2]; o.w = tmp[3];
    *(float4*)(T2 + base + j4 * 4) = o;
  }
}

// ---------------- K2: in_proj GEMM  T2(32768,64) @ W^T(64,256) -> T3 / T4 ----------------
__global__ __launch_bounds__(256) void k2_inproj(
    const float* __restrict__ T2, const float* __restrict__ ipwF,
    float* __restrict__ T3, float* __restrict__ T4)
{
  int mt = blockIdx.x, ct = blockIdx.y;
  int t = threadIdx.x;
  __shared__ float sA[64][68];  // [d][l]
  __shared__ float sB[64][68];  // [d][c]
  int row0 = mt * 64;
  for (int q = t; q < 1024; q += 256) {
    int l = q >> 4, d4 = (q & 15) * 4;
    float4 v = *(const float4*)(T2 + (size_t)(row0 + l) * 64 + d4);
    sA[d4][l] = v.x; sA[d4+1][l] = v.y; sA[d4+2][l] = v.z; sA[d4+3][l] = v.w;
  }
  for (int q = t; q < 1024; q += 256) {
    int cl = q >> 4, d4 = (q & 15) * 4;
    float4 v = *(const float4*)(ipwF + (size_t)(ct * 64 + cl) * 64 + d4);
    sB[d4][cl] = v.x; sB[d4+1][cl] = v.y; sB[d4+2][cl] = v.z; sB[d4+3][cl] = v.w;
  }
  __syncthreads();
  int ty = t >> 4, tx = t & 15;
  float acc[4][4];
#pragma unroll
  for (int i = 0; i < 4; ++i)
#pragma unroll
    for (int j = 0; j < 4; ++j) acc[i][j] = 0.f;
  for (int kk = 0; kk < 64; ++kk) {
    float4 a = *(const float4*)&sA[kk][ty * 4];
    float4 bq = *(const float4*)&sB[kk][tx * 4];
    float aa[4] = {a.x, a.y, a.z, a.w}, bb[4] = {bq.x, bq.y, bq.z, bq.w};
#pragma unroll
    for (int i = 0; i < 4; ++i)
#pragma unroll
      for (int j = 0; j < 4; ++j) acc[i][j] += aa[i] * bb[j];
  }
  int c0 = ct * 64 + tx * 4;
#pragma unroll
  for (int i = 0; i < 4; ++i) {
    size_t row = (size_t)row0 + ty * 4 + i;
    float4 o;
    if (c0 < 128) {
      o.x = acc[i][0]; o.y = acc[i][1]; o.z = acc[i][2]; o.w = acc[i][3];
      *(float4*)(T3 + row * 128 + c0) = o;
    } else {
      o.x = silu_(acc[i][0]); o.y = silu_(acc[i][1]); o.z = silu_(acc[i][2]); o.w = silu_(acc[i][3]);
      *(float4*)(T4 + row * 128 + (c0 - 128)) = o;
    }
  }
}

// ---------------- K3: depthwise conv 3x3 + SiLU -> U0, Ysum = sumDs*u (bf16 LDS staging) ----------------
__global__ __launch_bounds__(256) void k3_conv2(
    const float* __restrict__ T3, const void* cw, const void* cb, const void* Ds,
    const int* __restrict__ flag,
    float* __restrict__ U0, float* __restrict__ Ysum)
{
  bool isb = (*flag != 0);
  int e = blockIdx.x >> 6, h = blockIdx.x & 63, dc = blockIdx.y;
  int t = threadIdx.x;
  __shared__ unsigned short sI[3][66][65];  // bf16: [row][1+w][d], 25.7KB
  for (int idx = t; idx < 3 * 2 * 64; idx += 256) {
    int r = idx / 128, rem = idx % 128, side = rem >> 6, d = rem & 63;
    sI[r][side * 65][d] = 0;
  }
  for (int idx = t; idx < 3 * 64 * 64; idx += 256) {
    int r = idx >> 12, rem = idx & 4095, w = rem >> 6, d = rem & 63;
    int hh = h + r - 1;
    float v = 0.f;
    if (hh >= 0 && hh < 64) v = T3[((size_t)e * 4096 + hh * 64 + w) * 128 + dc * 64 + d];
    sI[r][1 + w][d] = f2bf(v);
  }
  __syncthreads();
  int d = t & 63, wq = t >> 6;
  int c2 = dc * 64 + d;
  float wt[9];
#pragma unroll
  for (int m = 0; m < 9; ++m) wt[m] = LD(cw, c2 * 9 + m, isb);
  float bias = LD(cb, c2, isb);
  float sd = LD(Ds, c2, isb) + LD(Ds, 128 + c2, isb) + LD(Ds, 256 + c2, isb) + LD(Ds, 384 + c2, isb);
  size_t eb = (size_t)e * 4096;
#pragma unroll
  for (int i = 0; i < 16; ++i) {
    int w = wq * 16 + i;
    float s = bias;
#pragma unroll
    for (int kh = 0; kh < 3; ++kh)
#pragma unroll
      for (int kw = 0; kw < 3; ++kw)
        s += wt[kh * 3 + kw] * b2f(sI[kh][w + kw][d]);
    s = silu_(s);
    U0[(eb + h * 64 + w) * 128 + c2] = s;
    Ysum[(eb + h * 64 + w) * 128 + c2] = sd * s;
  }
}

// ---------------- K5: x_dbl einsum; sU bf16-staged, sW f32 unpadded (broadcast) ----------------
__global__ __launch_bounds__(256) void k5_xdbl(
    const float* __restrict__ U0,
    const float* __restrict__ xpwF,
    float* __restrict__ dts4, float* __restrict__ Bb2, float* __restrict__ Cb2)
{
  int lt = blockIdx.x;   // 64 tiles of 64 along L
  int ek = blockIdx.y;   // e*4+k
  int e = ek >> 2, k = ek & 3;
  int ls0 = lt * 64;
  int t = threadIdx.x;
  __shared__ unsigned short sU[64][132];   // bf16 [l][d], 16.9KB (264B rows, 2-way banks = free)
  __shared__ float sW[36][128];            // f32, wave-uniform broadcast reads, 18.4KB
  for (int q = t; q < 1152; q += 256) {
    int c = q >> 5, d4 = (q & 31) * 4;
    float4 v = *(const float4*)(xpwF + ((size_t)k * 36 + c) * 128 + d4);
    *(float4*)&sW[c][d4] = v;
  }
  const bool rev = (k >= 2);
  const int trq = (k & 1);
  for (int idx = t; idx < 2048; idx += 256) {
    int l = idx >> 5, d4 = (idx & 31) * 4;
    int p = rev ? (4095 - ls0 - l) : (ls0 + l);
    int row = trq ? (((p & 63) << 6) | (p >> 6)) : p;
    float4 v = *(const float4*)(U0 + ((size_t)e * 4096 + row) * 128 + d4);
    sU[l][d4+0] = f2bf(v.x); sU[l][d4+1] = f2bf(v.y);
    sU[l][d4+2] = f2bf(v.z); sU[l][d4+3] = f2bf(v.w);
  }
  __syncthreads();
  int l = t & 63, cg = t >> 6;
  float acc[9];
#pragma unroll
  for (int j = 0; j < 9; ++j) acc[j] = 0.f;
  for (int dd = 0; dd < 32; ++dd) {
    uint2 up = *(const uint2*)&sU[l][dd * 4];   // 8B = 4 bf16 (8B-aligned: 264=8*33)
    float ua[4];
    ua[0] = __uint_as_float(up.x << 16);
    ua[1] = __uint_as_float(up.x & 0xffff0000u);
    ua[2] = __uint_as_float(up.y << 16);
    ua[3] = __uint_as_float(up.y & 0xffff0000u);
#pragma unroll
    for (int j = 0; j < 9; ++j) {
      float4 w4 = *(const float4*)&sW[cg * 9 + j][dd * 4];
      acc[j] += ua[0] * w4.x + ua[1] * w4.y + ua[2] * w4.z + ua[3] * w4.w;
    }
  }
  size_t row = (size_t)ek * 4096 + ls0 + l;
  if (cg == 0) {
    float4 o; o.x = acc[0]; o.y = acc[1]; o.z = acc[2]; o.w = acc[3];
    *(float4*)(dts4 + row * 4) = o;
#pragma unroll
    for (int j = 4; j < 9; ++j) Bb2[row * 16 + (j - 4)] = acc[j];
  } else {
#pragma unroll
    for (int j = 0; j < 9; ++j) {
      int c = cg * 9 + j;
      if (c < 20) Bb2[row * 16 + (c - 4)] = acc[j];
      else Cb2[row * 16 + (c - 20)] = acc[j];
    }
  }
}

// ---------------- K6a: chunk-local scan, LDS-staged dts4/B -> Hsh + Sdl ----------------
template<int NSTEPS>
__global__ __launch_bounds__(128) void k6a_chunk(
    const float* __restrict__ U0,
    const float* __restrict__ dts4, const float* __restrict__ Bb2,
    const float* __restrict__ a2tab, const void* dtw, const void* dtb,
    const int* __restrict__ flag,
    float* __restrict__ Hsh, float* __restrict__ Sdl)
{
  bool isb = (*flag != 0);
  int chunk = blockIdx.x, ek = blockIdx.y;
  int e = ek >> 2, k = ek & 3;
  int d = threadIdx.x;
  int ls0 = chunk * NSTEPS;
  __shared__ float4 sDt[NSTEPS];        // 512B
  __shared__ float4 sB[NSTEPS * 4];     // 2KB
  {
    const float4* srcd = (const float4*)(dts4 + ((size_t)ek * 4096 + ls0) * 4);
    const float4* srcb = (const float4*)(Bb2 + ((size_t)ek * 4096 + ls0) * 16);
    if (d < NSTEPS) sDt[d] = srcd[d];
    sB[d] = srcb[d];
  }
  float a2[16];
  {
    const float4* ap = (const float4*)(a2tab + ((size_t)k * 128 + d) * 16);
#pragma unroll
    for (int n4 = 0; n4 < 4; ++n4) {
      float4 v = ap[n4];
      a2[n4*4+0] = v.x; a2[n4*4+1] = v.y; a2[n4*4+2] = v.z; a2[n4*4+3] = v.w;
    }
  }
  float w0 = LD(dtw, ((size_t)k * 128 + d) * 4 + 0, isb);
  float w1 = LD(dtw, ((size_t)k * 128 + d) * 4 + 1, isb);
  float w2 = LD(dtw, ((size_t)k * 128 + d) * 4 + 2, isb);
  float w3 = LD(dtw, ((size_t)k * 128 + d) * 4 + 3, isb);
  float bd = LD(dtb, k * 128 + d, isb);
  float h[16];
#pragma unroll
  for (int n = 0; n < 16; ++n) h[n] = 0.f;
  float sdelta = 0.f;
  const bool rv = (k >= 2);
  const int tq = (k & 1);
  const float* ubase = U0 + (size_t)e * 4096 * 128 + d;
  __syncthreads();
#pragma unroll 2
  for (int s = 0; s < NSTEPS; ++s) {
    float4 s4 = sDt[s];
    float xv = bd + w0 * s4.x + w1 * s4.y + w2 * s4.z + w3 * s4.w;
    float dlt = softplus_(xv);
    int p = ls0 + s;
    int r0 = rv ? (4095 - p) : p;
    int row = tq ? (((r0 & 63) << 6) | (r0 >> 6)) : r0;
    float uu = ubase[(size_t)row * 128];
    float du = dlt * uu;
    sdelta += dlt;
#pragma unroll
    for (int n4 = 0; n4 < 4; ++n4) {
      float4 b4 = sB[s * 4 + n4];
      h[n4*4+0] = fmaf(EXP2R(dlt * a2[n4*4+0]), h[n4*4+0], du * b4.x);
      h[n4*4+1] = fmaf(EXP2R(dlt * a2[n4*4+1]), h[n4*4+1], du * b4.y);
      h[n4*4+2] = fmaf(EXP2R(dlt * a2[n4*4+2]), h[n4*4+2], du * b4.z);
      h[n4*4+3] = fmaf(EXP2R(dlt * a2[n4*4+3]), h[n4*4+3], du * b4.w);
    }
  }
  float* hp = Hsh + (size_t)chunk * 65536 + (size_t)ek * 2048 + (size_t)d * 16;
#pragma unroll
  for (int n4 = 0; n4 < 4; ++n4) {
    float4 o; o.x = h[n4*4]; o.y = h[n4*4+1]; o.z = h[n4*4+2]; o.w = h[n4*4+3];
    *(float4*)(hp + n4 * 4) = o;
  }
  Sdl[(size_t)chunk * 4096 + ek * 128 + d] = sdelta;
}

// ---------------- K6b: carry scan; prodA recomputed from sdelta; exclusive Carry out ----------------
__global__ __launch_bounds__(256) void k6b_carry(
    const float* __restrict__ Hsh, const float* __restrict__ Sdl,
    const float* __restrict__ a2tab,
    float* __restrict__ Carry)
{
  int idx = blockIdx.x * 256 + threadIdx.x;   // 65536 = ek*2048 + d*16 + n
  int ek = idx >> 11;
  int k = ek & 3;
  float a2 = a2tab[(size_t)k * 2048 + (idx & 2047)];
  int sidx = ek * 128 + ((idx & 2047) >> 4);
  float carry = 0.f;
  for (int c0 = 0; c0 < 128; c0 += 8) {
    float hv[8], pA[8];
#pragma unroll
    for (int j = 0; j < 8; ++j) {
      hv[j] = Hsh[(size_t)(c0 + j) * 65536 + idx];
      pA[j] = Sdl[(size_t)(c0 + j) * 4096 + sidx];
    }
#pragma unroll
    for (int j = 0; j < 8; ++j) pA[j] = EXP2R(a2 * pA[j]);
#pragma unroll
    for (int j = 0; j < 8; ++j) {
      Carry[(size_t)(c0 + j) * 65536 + idx] = carry;   // exclusive prefix
      carry = fmaf(pA[j], carry, hv[j]);
    }
  }
}

// ---------------- K6c: seeded chunk scan, LDS-staged dts4/B/C; atomic y-merge ----------------
// u-read row == output row for every direction k (reversal+transpose fold).
template<int NSTEPS>
__global__ __launch_bounds__(128) void k6c_apply(
    const float* __restrict__ U0,
    float* __restrict__ Ysum, const float* __restrict__ dts4,
    const float* __restrict__ Bb2, const float* __restrict__ Cb2,
    const float* __restrict__ a2tab, const void* dtw, const void* dtb,
    const float* __restrict__ Carry, const int* __restrict__ flag)
{
  bool isb = (*flag != 0);
  int chunk = blockIdx.x, ek = blockIdx.y;
  int e = ek >> 2, k = ek & 3;
  int d = threadIdx.x;
  int ls0 = chunk * NSTEPS;
  __shared__ float4 sDt[NSTEPS];        // 512B
  __shared__ float4 sB[NSTEPS * 4];     // 2KB
  __shared__ float4 sC[NSTEPS * 4];     // 2KB
  {
    const float4* srcd = (const float4*)(dts4 + ((size_t)ek * 4096 + ls0) * 4);
    const float4* srcb = (const float4*)(Bb2 + ((size_t)ek * 4096 + ls0) * 16);
    const float4* srcc = (const float4*)(Cb2 + ((size_t)ek * 4096 + ls0) * 16);
    if (d < NSTEPS) sDt[d] = srcd[d];
    sB[d] = srcb[d];
    sC[d] = srcc[d];
  }
  float a2[16];
  {
    const float4* ap = (const float4*)(a2tab + ((size_t)k * 128 + d) * 16);
#pragma unroll
    for (int n4 = 0; n4 < 4; ++n4) {
      float4 v = ap[n4];
      a2[n4*4+0] = v.x; a2[n4*4+1] = v.y; a2[n4*4+2] = v.z; a2[n4*4+3] = v.w;
    }
  }
  float w0 = LD(dtw, ((size_t)k * 128 + d) * 4 + 0, isb);
  float w1 = LD(dtw, ((size_t)k * 128 + d) * 4 + 1, isb);
  float w2 = LD(dtw, ((size_t)k * 128 + d) * 4 + 2, isb);
  float w3 = LD(dtw, ((size_t)k * 128 + d) * 4 + 3, isb);
  float bd = LD(dtb, k * 128 + d, isb);
  float h[16];
  {
    const float* cp = Carry + (size_t)chunk * 65536 + (size_t)ek * 2048 + (size_t)d * 16;
#pragma unroll
    for (int n = 0; n < 16; ++n) h[n] = cp[n];
  }
  const bool rv = (k >= 2);
  const int tq = (k & 1);
  const float* ubase = U0 + (size_t)e * 4096 * 128 + d;
  float* ybase = Ysum + (size_t)e * 4096 * 128 + d;
  __syncthreads();
#pragma unroll 2
  for (int s = 0; s < NSTEPS; ++s) {
    float4 s4 = sDt[s];
    float xv = bd + w0 * s4.x + w1 * s4.y + w2 * s4.z + w3 * s4.w;
    float dlt = softplus_(xv);
    int p = ls0 + s;
    int r0 = rv ? (4095 - p) : p;
    int row = tq ? (((r0 & 63) << 6) | (r0 >> 6)) : r0;   // == output row
    float uu = ubase[(size_t)row * 128];
    float du = dlt * uu;
    float ya = 0.f, yb = 0.f, yc = 0.f, yd = 0.f;
#pragma unroll
    for (int n4 = 0; n4 < 4; ++n4) {
      float4 b4 = sB[s * 4 + n4];
      float4 c4 = sC[s * 4 + n4];
      h[n4*4+0] = fmaf(EXP2R(dlt * a2[n4*4+0]), h[n4*4+0], du * b4.x);
      h[n4*4+1] = fmaf(EXP2R(dlt * a2[n4*4+1]), h[n4*4+1], du * b4.y);
      h[n4*4+2] = fmaf(EXP2R(dlt * a2[n4*4+2]), h[n4*4+2], du * b4.z);
      h[n4*4+3] = fmaf(EXP2R(dlt * a2[n4*4+3]), h[n4*4+3], du * b4.w);
      ya = fmaf(h[n4*4+0], c4.x, ya);
      yb = fmaf(h[n4*4+1], c4.y, yb);
      yc = fmaf(h[n4*4+2], c4.z, yc);
      yd = fmaf(h[n4*4+3], c4.w, yd);
    }
    atomicAdd(ybase + (size_t)row * 128, (ya + yb) + (yc + yd));
  }
}

// ---------------- K7b: out_norm LN * silu(z) -> out_proj (opwF direct) -> +residual -> P ----------------
__global__ __launch_bounds__(256) void k7b_out(
    const float* __restrict__ Ysum, const float* __restrict__ T4,
    const float* __restrict__ T1,
    const void* ong, const void* onb, const float* __restrict__ opwF,
    const void* scale_p, const int* __restrict__ flag,
    float* __restrict__ P)
{
  bool isb = (*flag != 0);
  int bid = blockIdx.x; int e = bid >> 7, lt = bid & 127;
  int l0 = lt * 32;
  int t = threadIdx.x;
  __shared__ float sY[32][132];
  __shared__ float sMu[32], sRs[32];
  __shared__ float sPs[32][8], sPq[32][8];
  __shared__ float sP[64][33];
  for (int q = t; q < 1024; q += 256) {
    int l = q >> 5, d4 = (q & 31) * 4;
    float4 v = *(const float4*)(Ysum + ((size_t)e * 4096 + l0 + l) * 128 + d4);
    *(float4*)&sY[l][d4] = v;
  }
  __syncthreads();
  {
    int l = t & 31, g = t >> 5;
    float s = 0.f, q2 = 0.f;
#pragma unroll
    for (int j = 0; j < 16; ++j) { float v = sY[l][g * 16 + j]; s += v; q2 += v * v; }
    sPs[l][g] = s; sPq[l][g] = q2;
  }
  __syncthreads();
  if (t < 32) {
    float s = 0.f, q2 = 0.f;
#pragma unroll
    for (int g = 0; g < 8; ++g) { s += sPs[t][g]; q2 += sPq[t][g]; }
    float mu = s * (1.f / 128.f);
    float var = q2 * (1.f / 128.f) - mu * mu;
    sMu[t] = mu; sRs[t] = rsqrtf(var + 1e-5f);
  }
  __syncthreads();
  for (int idx = t; idx < 4096; idx += 256) {
    int l = idx >> 7, dd2 = idx & 127;
    float v = (sY[l][dd2] - sMu[l]) * sRs[l] * LD(ong, dd2, isb) + LD(onb, dd2, isb);
    v *= T4[((size_t)e * 4096 + l0 + l) * 128 + dd2];
    sY[l][dd2] = v;
  }
  __syncthreads();
  float ops = 1.f + LD(scale_p, 0, isb);
  {
    int l = t & 31, cg = t >> 5;
    const float4* wob = (const float4*)opwF;
    float acc[8];
#pragma unroll
    for (int j = 0; j < 8; ++j) acc[j] = 0.f;
    for (int dd = 0; dd < 32; ++dd) {
      float4 v4 = *(const float4*)&sY[l][dd * 4];
      float va[4] = {v4.x, v4.y, v4.z, v4.w};
#pragma unroll
      for (int j = 0; j < 8; ++j) {
        float4 w4 = wob[(cg * 8 + j) * 32 + dd];   // half-wave broadcast, L1-resident
        acc[j] += va[0] * w4.x + va[1] * w4.y + va[2] * w4.z + va[3] * w4.w;
      }
    }
#pragma unroll
    for (int j = 0; j < 8; ++j) {
      int c = cg * 8 + j;
      sP[c][l] = acc[j] + ops * T1[((size_t)e * 4096 + l0 + l) * 64 + c];
    }
  }
  __syncthreads();
  for (int q = t; q < 512; q += 256) {
    int c = q >> 3, lq = (q & 7) * 4;
    float4 o; o.x = sP[c][lq]; o.y = sP[c][lq+1]; o.z = sP[c][lq+2]; o.w = sP[c][lq+3];
    *(float4*)(P + ((size_t)e * 64 + c) * 4096 + l0 + lq) = o;
  }
}

// ---------------- K7c: instance-norm over L per (e,c) + leaky relu + out ----------------
__global__ __launch_bounds__(256) void k7c_final(
    const float* __restrict__ P, const void* gamma, const void* beta,
    const int* __restrict__ flag, void* __restrict__ out)
{
  bool isb = (*flag != 0);
  int bid = blockIdx.x; int e = bid >> 6, c = bid & 63;
  int b = e & 3, br = e >> 2;
  int cg = br * 64 + c;
  int t = threadIdx.x;
  const float* p = P + ((size_t)e * 64 + c) * 4096;
  float s = 0.f, q2 = 0.f;
  for (int q = t; q < 1024; q += 256) {
    float4 v = *(const float4*)(p + q * 4);
    s += v.x + v.y + v.z + v.w;
    q2 += v.x * v.x + v.y * v.y + v.z * v.z + v.w * v.w;
  }
#pragma unroll
  for (int off = 1; off < 64; off <<= 1) { s += __shfl_xor(s, off); q2 += __shfl_xor(q2, off); }
  __shared__ float rS[4], rQ[4];
  if ((t & 63) == 0) { rS[t >> 6] = s; rQ[t >> 6] = q2; }
  __syncthreads();
  float ts = rS[0] + rS[1] + rS[2] + rS[3];
  float tq = rQ[0] + rQ[1] + rQ[2] + rQ[3];
  float mu = ts * (1.f / 4096.f);
  float var = tq * (1.f / 4096.f) - mu * mu;
  float rsg = rsqrtf(var + 1e-5f);
  float gm = LD(gamma, cg, isb), bt = LD(beta, cg, isb);
  size_t obase = ((size_t)(b * 128 + cg)) * 4096;
  for (int q = t; q < 1024; q += 256) {
    float4 v = *(const float4*)(p + q * 4);
    float o0 = (v.x - mu) * rsg * gm + bt; o0 = o0 > 0.f ? o0 : 0.01f * o0;
    float o1 = (v.y - mu) * rsg * gm + bt; o1 = o1 > 0.f ? o1 : 0.01f * o1;
    float o2 = (v.z - mu) * rsg * gm + bt; o2 = o2 > 0.f ? o2 : 0.01f * o2;
    float o3 = (v.w - mu) * rsg * gm + bt; o3 = o3 > 0.f ? o3 : 0.01f * o3;
    if (isb) {
      unsigned short* op = (unsigned short*)out + obase;
      unsigned lo = (unsigned)f2bf(o0) | ((unsigned)f2bf(o1) << 16);
      unsigned hi = (unsigned)f2bf(o2) | ((unsigned)f2bf(o3) << 16);
      uint2 u; u.x = lo; u.y = hi;
      *(uint2*)(op + q * 4) = u;
    } else {
      float* op = (float*)out + obase;
      float4 o; o.x = o0; o.y = o1; o.z = o2; o.w = o3;
      *(float4*)(op + q * 4) = o;
    }
  }
}

extern "C" void kernel_launch(void* const* d_in, const int* in_sizes, int n_in,
                              void* d_out, int out_size, void* d_ws, size_t ws_size,
                              hipStream_t stream) {
  (void)in_sizes; (void)n_in; (void)out_size; (void)ws_size;
  const void* x      = d_in[0];
  const void* dw_w   = d_in[1];
  const void* dw_b   = d_in[2];
  const void* scale  = d_in[3];
  const void* ln1_g  = d_in[4];
  const void* ln1_b  = d_in[5];
  const void* ipw    = d_in[6];
  const void* conv_w = d_in[7];
  const void* conv_b = d_in[8];
  const void* xpw    = d_in[9];
  const void* dtw    = d_in[10];
  const void* dtb    = d_in[11];
  const void* alog   = d_in[12];
  const void* Ds     = d_in[13];
  const void* ong    = d_in[14];
  const void* onb    = d_in[15];
  const void* opw    = d_in[16];
  const void* ing    = d_in[17];
  const void* inb    = d_in[18];

  float* ws = (float*)d_ws;
  float* T1   = ws;                  // (E,L,64)  xd rows                    8.4MB
  float* T2   = ws + 2097152;        // (E,L,64)  xln -> dts4 -> P           8.4MB
  float* T3   = ws + 4194304;        // (E,L,128) conv-in -> Bb2+Cb2        16.8MB
  float* T4   = ws + 8388608;        // (E,L,128) silu(z)                   16.8MB
  float* U0   = ws + 12582912;       // (E,L,128) xc rows [h*64+w][d]       16.8MB
  float* Hsh  = ws + 16777216;       // 128 x (32ek x 128d x 16n) h-local   33.5MB
  float* Carry= ws + 25165824;       // same shape, exclusive carries       33.5MB
  float* Sdl  = ws + 33554432;       // 128 x (32ek x 128d) sdelta           2.1MB
  float* Ysum = ws + 34078720;       // (E,L,128) direction-merged y        16.8MB
  float* Bb2  = T3;                  // (EK,L,16)
  float* Cb2  = T3 + 2097152;        // (EK,L,16)
  float* dts4 = T2;                  // (EK,L,4) — overlays dead xln
  int* flag   = (int*)(ws + 38273024);
  float* a2tab= ws + 38273040;       // 8192
  float* xpwF = ws + 38281232;       // 18432 (K,36,128)
  float* opwF = ws + 38299664;       // 8192  (64,128)
  float* ipwF = ws + 38307856;       // 16384 (256,64); end ~153.3MB

  hipLaunchKernelGGL(kdet, dim3(1), dim3(64), 0, stream, x, flag);
  hipLaunchKernelGGL(kprep, dim3(72), dim3(256), 0, stream, alog, xpw, opw, ipw, flag, a2tab, xpwF, opwF, ipwF);
  hipLaunchKernelGGL(k0_conv_ln, dim3(512), dim3(256), 0, stream, x, dw_w, dw_b, ln1_g, ln1_b, flag, T1, T2);
  hipLaunchKernelGGL(k2_inproj, dim3(512, 4), dim3(256), 0, stream, T2, ipwF, T3, T4);
  hipLaunchKernelGGL(k3_conv2, dim3(512, 2), dim3(256), 0, stream, T3, conv_w, conv_b, Ds, flag, U0, Ysum);
  hipLaunchKernelGGL(k5_xdbl, dim3(64, 32), dim3(256), 0, stream, U0, xpwF, dts4, Bb2, Cb2);
  hipLaunchKernelGGL(k6a_chunk<32>, dim3(128, 32), dim3(128), 0, stream, U0, dts4, Bb2, a2tab, dtw, dtb, flag, Hsh, Sdl);
  hipLaunchKernelGGL(k6b_carry, dim3(256), dim3(256), 0, stream, Hsh, Sdl, a2tab, Carry);
  hipLaunchKernelGGL(k6c_apply<32>, dim3(128, 32), dim3(128), 0, stream, U0, Ysum, dts4, Bb2, Cb2, a2tab, dtw, dtb, Carry, flag);
  hipLaunchKernelGGL(k7b_out, dim3(1024), dim3(256), 0, stream, Ysum, T4, T1, ong, onb, opwF, scale, flag, T2);
  hipLaunchKernelGGL(k7c_final, dim3(512), dim3(256), 0, stream, T2, ing, inb, flag, d_out);
}